// Round 8
// baseline (156.494 us; speedup 1.0000x reference)
//
#include <hip/hip_runtime.h>
#include <hip/hip_bf16.h>

// ---------------- problem constants ----------------
#define Bc   8
#define Cc   256
#define Hc   64
#define Wc   64
#define HWc  4096
#define KDIM 1024          // M*C

#define LOSS_IDX   8388608
#define OFFS_BASE  8388609        // offsets output base in d_out

// ---------------- ws layout (bytes) ----------------
#define XT_OFF     0u              // bf16 [B][HW][512] hi   33,554,432
#define HEAD_OFF   33554432u       // Xlo bf16 [B][HW][512]  33,554,432 (conv-only)
#define WBF_OFF    100663296u      // bf16 [C][KDIM]          524,288
#define ATTN_OFF   101187584u      // f32 [B][M][HW]          524,288
#define ALPHA_OFF  101711872u      // f32 [8]
#define LOSSP_OFF  101712128u      // f32 [256]
#define WREP_OFF   101714176u      // wconv blob              221,184 (8 steps x 1728 granules x 16B)
#define ZPAGE_OFF  101935360u      // 256 B zeros

typedef unsigned short u16;
typedef __attribute__((ext_vector_type(8))) short bf16x8;
typedef __attribute__((ext_vector_type(8))) unsigned short u16x8;
typedef __attribute__((ext_vector_type(4))) float f32x4;

static __device__ __forceinline__ u16 f2bf(float f) {
    unsigned int u = __float_as_uint(f);
    unsigned int r = (u + 0x7FFFu + ((u >> 16) & 1u)) >> 16;
    return (u16)r;
}
static __device__ __forceinline__ float bf2f(u16 h) {
    return __uint_as_float(((unsigned int)h) << 16);
}

// ---------------- kernel 1: pack X -> channel-last bf16 hi/lo ----------------
__global__ __launch_bounds__(256) void pack_x(const float* __restrict__ Fx,
                                              const float* __restrict__ Fc,
                                              u16* __restrict__ Xt, u16* __restrict__ Xlo) {
    __shared__ float tile[32][33];
    const int blk = blockIdx.x;               // 16384
    const int b = blk >> 11;
    const int rem = blk & 2047;
    const int hw0 = (rem >> 4) << 5;
    const int c0 = (rem & 15) << 5;           // 0..480
    const int tid = threadIdx.x;
    const int ci = tid >> 5, hwi = tid & 31;
#pragma unroll
    for (int it = 0; it < 4; ++it) {
        const int cc = c0 + ci + it * 8;
        const float* src = (cc < 256) ? Fx + (((size_t)b << 8) + cc) * HWc
                                      : Fc + (((size_t)b << 8) + cc - 256) * HWc;
        tile[ci + it * 8][hwi] = src[hw0 + hwi];
    }
    __syncthreads();
    const int pix = tid >> 3, c4 = (tid & 7) << 2;
    const size_t obase = (((size_t)b << 12) + hw0 + pix) * 512 + c0 + c4;
    ushort4 hi4, lo4;
#pragma unroll
    for (int k = 0; k < 4; ++k) {
        const float v = tile[c4 + k][pix];
        const u16 h = f2bf(v);
        ((u16*)&hi4)[k] = h;
        ((u16*)&lo4)[k] = f2bf(v - bf2f(h));
    }
    *(ushort4*)(Xt + obase) = hi4;
    *(ushort4*)(Xlo + obase) = lo4;
}

// ---------------- kernel 2: prep — wfuse cast + wconv swizzled blob + zpage ----------------
__global__ __launch_bounds__(256) void prep(const float* __restrict__ wf,
                                            u16* __restrict__ wbf,
                                            const float* __restrict__ w_off,
                                            const float* __restrict__ w_attn,
                                            u16* __restrict__ wconv,
                                            float* __restrict__ zpage) {
    const int tid = threadIdx.x;
    if (blockIdx.x < 256) {
        const int i = blockIdx.x * 256 + tid;
        const float4 v = *(const float4*)(wf + (size_t)i * 4);
        ushort4 o;
        o.x = f2bf(v.x); o.y = f2bf(v.y); o.z = f2bf(v.z); o.w = f2bf(v.w);
        *(ushort4*)(wbf + (size_t)i * 4) = o;
    } else if (blockIdx.x < 264) {            // EXACTLY 8 steps
        const int step = blockIdx.x - 256;
        for (int n = tid; n < 1728; n += 256) {
            const int par = n & 1;
            const int slot = (n >> 1) & 3;
            const int pair = (n >> 3) % 6;
            const int tap = (n / 48) % 9;
            const int prec = (n / 432) & 1;
            const int sub = n / 864;
            const int oc = pair * 2 + par;
            const int c = slot ^ (pair & 3);
            const int ch = step * 64 + sub * 32 + c * 8;
            u16x8 out;
#pragma unroll
            for (int j = 0; j < 8; ++j) {
                const float v = (oc < 8)
                    ? w_off[((size_t)oc * 512 + ch + j) * 9 + tap]
                    : w_attn[((size_t)(oc - 8) * 512 + ch + j) * 9 + tap];
                const u16 h = f2bf(v);
                out[j] = prec ? f2bf(v - bf2f(h)) : h;
            }
            *(u16x8*)(wconv + ((size_t)step * 1728 + n) * 8) = out;
        }
    } else {
        if (tid < 64) zpage[tid] = 0.f;
    }
}

// ---------------- kernel 3: conv as split-bf16 MFMA implicit GEMM ----------------
#define XBUF_STR 67584
#define XPRC_STR 33792
#define XROW_STR 8448
#define B_BASE   135168
__global__ __launch_bounds__(512) void conv_mfma(
    const u16* __restrict__ Xt, const u16* __restrict__ Xlo,
    const u16* __restrict__ wconv, const float* __restrict__ zpage,
    const float* __restrict__ b_off, const float* __restrict__ b_attn,
    float* __restrict__ dout, float* __restrict__ attnb, float* __restrict__ lossp) {
    __shared__ char smem[163840];

    const int tid = threadIdx.x;
    const int wv = tid >> 6, lane = tid & 63;
    const int gp = wv >> 2, qd = wv & 3;
    const int l15 = lane & 15, g = lane >> 4;
    const int b = blockIdx.x >> 5;
    const int h0 = (blockIdx.x & 31) * 2;
    const int wrow = qd >> 1, wcol0 = (qd & 1) * 32;

    if (tid < 256) {
        const int bu = tid >> 7, pr = (tid >> 6) & 1, rr = (tid >> 4) & 3;
        const int hp = (tid >> 3) & 1, cc = tid & 7;
        const int p = hp ? 65 : 0;
        const float4 z = {0.f, 0.f, 0.f, 0.f};
        *(float4*)(smem + bu * XBUF_STR + pr * XPRC_STR + rr * XROW_STR + p * 128 + cc * 16) = z;
    }

    int pre[2][3];
#pragma unroll
    for (int f = 0; f < 2; ++f)
#pragma unroll
        for (int dx = 0; dx < 3; ++dx) {
            const int p = wcol0 + f * 16 + l15 + dx;      // 0..65
            pre[f][dx] = wrow * XROW_STR + p * 128 + ((((gp << 2) | g) ^ (p & 7)) << 4);
        }
    const int bpair = l15 >> 1, bpar = l15 & 1;
    const int vb = B_BASE + gp * 13824 + bpair * 128 + ((g ^ (bpair & 3)) << 5) + bpar * 16;

    auto stage_X = [&](int step, int buf) {
#pragma unroll
        for (int k = 0; k < 9; ++k) {
            const int f = wv * 9 + k;                     // 0..71
            const int prec = f / 36, rr = (f / 9) & 3, i = f % 9;
            const int p = i * 8 + (lane >> 3);
            const int c = (lane & 7) ^ (p & 7);
            const int col = p - 1;
            const int h = h0 - 1 + rr;
            const bool act = (p >= 1) && (p <= 64);
            const u16* srcb = prec ? Xlo : Xt;
            const char* gsrc = (h >= 0 && h < 64)
                ? (const char*)(srcb + (((size_t)((b << 12) + h * 64 + col)) << 9) + step * 64 + c * 8)
                : (const char*)zpage + ((lane & 7) << 4);
            char* ldst = smem + buf * XBUF_STR + prec * XPRC_STR + rr * XROW_STR + i * 1024;
            if (act)
                __builtin_amdgcn_global_load_lds(
                    (const __attribute__((address_space(1))) unsigned int*)gsrc,
                    (__attribute__((address_space(3))) unsigned int*)ldst, 16, 0, 0);
        }
    };
    auto stage_B = [&](int step) {
        for (int i = wv; i < 27; i += 8) {
            const char* gsrc = (const char*)wconv + (((size_t)step * 1728) + i * 64 + lane) * 16;
            char* ldst = smem + B_BASE + i * 1024;
            __builtin_amdgcn_global_load_lds(
                (const __attribute__((address_space(1))) unsigned int*)gsrc,
                (__attribute__((address_space(3))) unsigned int*)ldst, 16, 0, 0);
        }
    };

    __syncthreads();
    stage_X(0, 0);
    stage_B(0);
    __syncthreads();

    f32x4 acc0 = {}, acc1 = {};

    for (int step = 0; step < 8; ++step) {
        if (step < 7) {
            stage_X(step + 1, (step + 1) & 1);
            asm volatile("s_waitcnt vmcnt(9)" ::: "memory");
        } else {
            asm volatile("s_waitcnt vmcnt(0)" ::: "memory");
        }
        __builtin_amdgcn_s_barrier();
        __builtin_amdgcn_sched_barrier(0);

#pragma unroll
        for (int tap = 0; tap < 9; ++tap) {
            const int dy = tap / 3, dx = tap % 3;
            const bf16x8 bh = *(const bf16x8*)(smem + vb + tap * 768);
            const bf16x8 bl = *(const bf16x8*)(smem + vb + 6912 + tap * 768);
            const bf16x8 a0h = *(const bf16x8*)(smem + pre[0][dx] + dy * XROW_STR);
            const bf16x8 a1h = *(const bf16x8*)(smem + pre[1][dx] + dy * XROW_STR);
            const bf16x8 a0l = *(const bf16x8*)(smem + pre[0][dx] + XPRC_STR + dy * XROW_STR);
            const bf16x8 a1l = *(const bf16x8*)(smem + pre[1][dx] + XPRC_STR + dy * XROW_STR);
            acc0 = __builtin_amdgcn_mfma_f32_16x16x32_bf16(a0h, bh, acc0, 0, 0, 0);
            acc1 = __builtin_amdgcn_mfma_f32_16x16x32_bf16(a1h, bh, acc1, 0, 0, 0);
            acc0 = __builtin_amdgcn_mfma_f32_16x16x32_bf16(a0h, bl, acc0, 0, 0, 0);
            acc1 = __builtin_amdgcn_mfma_f32_16x16x32_bf16(a1h, bl, acc1, 0, 0, 0);
            acc0 = __builtin_amdgcn_mfma_f32_16x16x32_bf16(a0l, bh, acc0, 0, 0, 0);
            acc1 = __builtin_amdgcn_mfma_f32_16x16x32_bf16(a1l, bh, acc1, 0, 0, 0);
        }

        __builtin_amdgcn_sched_barrier(0);
        __builtin_amdgcn_s_barrier();
        __builtin_amdgcn_sched_barrier(0);
        if (step < 7) stage_B(step + 1);
        const int d = (step & 1) ? -XBUF_STR : XBUF_STR;
#pragma unroll
        for (int f = 0; f < 2; ++f)
#pragma unroll
            for (int dx = 0; dx < 3; ++dx) pre[f][dx] += d;
    }

    __syncthreads();
    float* eL = (float*)smem;        // [2 groups][12 oc][128 pix]
    if (l15 < 12) {
#pragma unroll
        for (int r = 0; r < 4; ++r) {
            const int px0 = wrow * 64 + wcol0 + g * 4 + r;
            eL[(gp * 12 + l15) * 128 + px0] = acc0[r];
            eL[(gp * 12 + l15) * 128 + px0 + 16] = acc1[r];
        }
    }
    __syncthreads();
    float labs = 0.f;
    if (tid < 256) {
        const int oc = tid >> 5, seg = tid & 31;
        const float4 v0 = *(const float4*)&eL[oc * 128 + seg * 4];
        const float4 v1 = *(const float4*)&eL[(12 + oc) * 128 + seg * 4];
        const float bo = b_off[oc];
        float4 o;
        o.x = v0.x + v1.x + bo; o.y = v0.y + v1.y + bo;
        o.z = v0.z + v1.z + bo; o.w = v0.w + v1.w + bo;
        *(float4*)(dout + OFFS_BASE + (((size_t)b * 8 + oc) << 12) + h0 * 64 + seg * 4) = o;
        labs = fabsf(o.x) + fabsf(o.y) + fabsf(o.z) + fabsf(o.w);
    } else if (tid < 384) {
        const int t2 = tid - 256;
        const int oc = t2 >> 5, seg = t2 & 31;
        const float4 v0 = *(const float4*)&eL[(8 + oc) * 128 + seg * 4];
        const float4 v1 = *(const float4*)&eL[(20 + oc) * 128 + seg * 4];
        const float ba = b_attn[oc];
        float4 o;
        o.x = 1.f / (1.f + expf(-(v0.x + v1.x + ba)));
        o.y = 1.f / (1.f + expf(-(v0.y + v1.y + ba)));
        o.z = 1.f / (1.f + expf(-(v0.z + v1.z + ba)));
        o.w = 1.f / (1.f + expf(-(v0.w + v1.w + ba)));
        *(float4*)(attnb + (((size_t)b * 4 + oc) << 12) + h0 * 64 + seg * 4) = o;
    }
#pragma unroll
    for (int off = 32; off; off >>= 1) labs += __shfl_down(labs, off);
    float* wr = (float*)(smem + 14336);
    if (lane == 0) wr[wv] = labs;
    __syncthreads();
    if (tid == 0) {
        float s = 0.f;
#pragma unroll
        for (int i = 0; i < 8; ++i) s += wr[i];
        lossp[blockIdx.x] = s;
    }
}

// ---------------- kernel 4: loss reduce + alpha MLP ----------------
__global__ __launch_bounds__(256) void finalize_small(
    const float* __restrict__ lossp, const float* __restrict__ t,
    const float* __restrict__ w1, const float* __restrict__ b1,
    const float* __restrict__ w2, const float* __restrict__ b2,
    float* __restrict__ dout, float* __restrict__ alpha) {
    __shared__ float sd[4];
    const int tid = threadIdx.x;
    float s = lossp[tid];
#pragma unroll
    for (int off = 32; off; off >>= 1) s += __shfl_down(s, off);
    if ((tid & 63) == 0) sd[tid >> 6] = s;
    __syncthreads();
    if (tid == 0) dout[LOSS_IDX] = (sd[0] + sd[1] + sd[2] + sd[3]) * (1.f / 262144.f);

    for (int b = 0; b < 8; ++b) {
        __syncthreads();
        float v = 0.f;
        if (tid < 128) v = fmaxf(fmaf(t[b], w1[tid], b1[tid]), 0.f) * w2[tid];
#pragma unroll
        for (int off = 32; off; off >>= 1) v += __shfl_down(v, off);
        if ((tid & 63) == 0) sd[tid >> 6] = v;
        __syncthreads();
        if (tid == 0) alpha[b] = 1.f / (1.f + expf(-(sd[0] + sd[1] + b2[0])));
    }
}

// ---------------- kernel 5: FUSED gather + fuse-GEMM + blend (v3: occupancy) ----------------
// grid 1024 = (b 8) x (32-pix tile 128); 512 threads = 8 waves, each wave owns 32 co.
// LDS 2 x 16 KB -> 4 blocks/CU (thread-capped) = 32 waves/CU.
// Per m: gather(m+1) into buf^1 issued BEFORE GEMM(m); ONE barrier per m.
__global__ __launch_bounds__(512, 4) void fused_tail(
    const u16* __restrict__ Xt, const float* __restrict__ attnb,
    const float* __restrict__ Wp, const u16* __restrict__ wbf,
    const float* __restrict__ Fx, const float* __restrict__ bfuse,
    const float* __restrict__ alpha, float* __restrict__ dout) {
    __shared__ u16 Asl[2][8192];             // 2 x (32 pix x 256 ch) = 2 x 16 KB

    const int tid = threadIdx.x;
    const int wv = tid >> 6, lane = tid & 63;
    const int l15 = lane & 15, g = lane >> 4;
    const int hl = lane >> 5, l32 = lane & 31;
    const int b = blockIdx.x >> 7;
    const int pix0 = (blockIdx.x & 127) << 5;   // 32-pixel tile (within one image row)
    const int h = pix0 >> 6;
    const float ysh = -1.f + h * (2.f / 63.f);

    const u16* gbase = Xt + ((size_t)b << 12) * 512 + 256 + l32 * 8;   // F_c channels

    f32x4 acc[2][2] = {};

    auto gather = [&](int m, int buf) {
        char* ab = (char*)Asl[buf];
        const float wr0 = Wp[m * 4 + 0], wr1 = Wp[m * 4 + 1];
        const float wr2 = Wp[m * 4 + 2], wr3 = Wp[m * 4 + 3];
#pragma unroll
        for (int it = 0; it < 4; ++it) {
            const int pi = wv * 4 + it;
            const int p = pix0 + pi;
            const int wc = p & 63;
            const float off0 = dout[OFFS_BASE + ((size_t)(b * 8 + 2 * m) << 12) + p];
            const float off1 = dout[OFFS_BASE + ((size_t)(b * 8 + 2 * m + 1) << 12) + p];
            const float av = attnb[((size_t)(b * 4 + m) << 12) + p];
            const float xsw = -1.f + wc * (2.f / 63.f);
            float ac[8] = {};
#pragma unroll
            for (int r = 0; r < 4; ++r) {
                const float bpy = (r < 2) ? -0.5f : 0.5f;
                const float bpx = (r & 1) ? 0.5f : -0.5f;
                const float c0 = ysh + bpy + off0;   // used as gx (reference quirk)
                const float c1 = xsw + bpx + off1;   // used as gy
                const float ix = (c0 + 1.f) * 31.5f;
                const float iy = (c1 + 1.f) * 31.5f;
                const float x0 = floorf(ix), y0 = floorf(iy);
                const float wx1 = ix - x0, wx0 = 1.f - wx1;
                const float wy1 = iy - y0, wy0 = 1.f - wy1;
                const float wr = (r == 0) ? wr0 : (r == 1) ? wr1 : (r == 2) ? wr2 : wr3;
                const float xf = x0 + hl;            // this half-wave's x corner
                const float wxl = (hl ? wx1 : wx0) * wr;
#pragma unroll
                for (int cc = 0; cc < 2; ++cc) {
                    const float yf = y0 + cc;
                    if (yf >= 0.f && yf < 64.f && xf >= 0.f && xf < 64.f) {
                        const int idx = (((int)yf) << 6) + (int)xf;
                        const u16x8 v = *(const u16x8*)(gbase + (size_t)idx * 512);
                        const float w = wxl * (cc ? wy1 : wy0);
#pragma unroll
                        for (int j = 0; j < 8; ++j)
                            ac[j] = fmaf(w, bf2f(v[j]), ac[j]);
                    }
                }
            }
#pragma unroll
            for (int j = 0; j < 8; ++j) ac[j] += __shfl_xor(ac[j], 32);
            if (lane < 32) {
                u16x8 o;
#pragma unroll
                for (int j = 0; j < 8; ++j) o[j] = f2bf(av * ac[j]);
                *(u16x8*)(ab + pi * 512 + ((l32 * 16) ^ ((pi & 7) << 4))) = o;
            }
        }
    };

    gather(0, 0);
    __syncthreads();

    for (int m = 0; m < 4; ++m) {
        if (m < 3) gather(m + 1, (m + 1) & 1);   // loads in flight over GEMM(m)

        const char* ab = (const char*)Asl[m & 1];
#pragma unroll
        for (int kk = 0; kk < 8; ++kk) {
            bf16x8 af[2], bfr[2];
#pragma unroll
            for (int i = 0; i < 2; ++i) {
                const int r = i * 16 + l15;
                af[i] = *(const bf16x8*)(ab + r * 512 + ((kk * 64 + g * 16) ^ ((r & 7) << 4)));
            }
#pragma unroll
            for (int j = 0; j < 2; ++j)
                bfr[j] = *(const bf16x8*)(wbf + ((size_t)(wv * 32 + j * 16 + l15) << 10) +
                                          m * 256 + kk * 32 + g * 8);
#pragma unroll
            for (int i = 0; i < 2; ++i)
#pragma unroll
                for (int j = 0; j < 2; ++j)
                    acc[i][j] = __builtin_amdgcn_mfma_f32_16x16x32_bf16(af[i], bfr[j], acc[i][j], 0, 0, 0);
        }
        __syncthreads();                      // buf[m&1] free; buf[(m+1)&1] ready
    }

    const float al = alpha[b], il = 1.f - al;
#pragma unroll
    for (int i = 0; i < 2; ++i) {
        const int pixb = pix0 + i * 16 + g * 4;
#pragma unroll
        for (int j = 0; j < 2; ++j) {
            const int co = wv * 32 + j * 16 + l15;
            const float bias = bfuse[co];
            const size_t idx = (((size_t)b << 8) + co) * HWc + pixb;
            const float4 fx = *(const float4*)(Fx + idx);
            const f32x4 v = acc[i][j];
            float4 o;
            o.x = al * (v[0] + bias) + il * fx.x;
            o.y = al * (v[1] + bias) + il * fx.y;
            o.z = al * (v[2] + bias) + il * fx.z;
            o.w = al * (v[3] + bias) + il * fx.w;
            *(float4*)(dout + idx) = o;
        }
    }
}

// ---------------- launcher ----------------
extern "C" void kernel_launch(void* const* d_in, const int* in_sizes, int n_in,
                              void* d_out, int out_size, void* d_ws, size_t ws_size,
                              hipStream_t stream) {
    const float* F_x    = (const float*)d_in[0];
    const float* F_c    = (const float*)d_in[1];
    const float* t      = (const float*)d_in[2];
    const float* w_off  = (const float*)d_in[3];
    const float* b_off  = (const float*)d_in[4];
    const float* w_attn = (const float*)d_in[5];
    const float* b_attn = (const float*)d_in[6];
    const float* Wp     = (const float*)d_in[7];
    const float* w_fuse = (const float*)d_in[8];
    const float* b_fuse = (const float*)d_in[9];
    const float* w1     = (const float*)d_in[10];
    const float* b1     = (const float*)d_in[11];
    const float* w2     = (const float*)d_in[12];
    const float* b2     = (const float*)d_in[13];
    float* out = (float*)d_out;

    char* ws = (char*)d_ws;
    u16*   Xt    = (u16*)(ws + XT_OFF);
    u16*   Xlo   = (u16*)(ws + HEAD_OFF);
    u16*   wbf   = (u16*)(ws + WBF_OFF);
    float* attnb = (float*)(ws + ATTN_OFF);
    float* alphb = (float*)(ws + ALPHA_OFF);
    float* lossp = (float*)(ws + LOSSP_OFF);
    u16*   wconv = (u16*)(ws + WREP_OFF);
    float* zpage = (float*)(ws + ZPAGE_OFF);

    pack_x<<<dim3(16384), dim3(256), 0, stream>>>(F_x, F_c, Xt, Xlo);
    prep<<<dim3(265), dim3(256), 0, stream>>>(w_fuse, wbf, w_off, w_attn, wconv, zpage);
    conv_mfma<<<dim3(256), dim3(512), 0, stream>>>(Xt, Xlo, wconv, zpage, b_off, b_attn,
                                                   out, attnb, lossp);
    finalize_small<<<dim3(1), dim3(256), 0, stream>>>(lossp, t, w1, b1, w2, b2, out, alphb);
    fused_tail<<<dim3(1024), dim3(512), 0, stream>>>(Xt, attnb, Wp, wbf, F_x, b_fuse,
                                                     alphb, out);
}

// Round 9
// 141.031 us; speedup vs baseline: 1.1096x; 1.1096x over previous
//
#include <hip/hip_runtime.h>
#include <hip/hip_bf16.h>

// ---------------- problem constants ----------------
#define Bc   8
#define Cc   256
#define Hc   64
#define Wc   64
#define HWc  4096
#define KDIM 1024          // M*C

#define LOSS_IDX   8388608
#define OFFS_BASE  8388609        // offsets output base in d_out

// ---------------- ws layout (bytes) ----------------
#define XT_OFF     0u              // bf16 [B][HW][512] hi   33,554,432
#define HEAD_OFF   33554432u       // Xlo bf16 (conv) THEN head bf16 [NROW][KDIM] (tail)
#define WBF_OFF    100663296u      // bf16 [C][KDIM]          524,288
#define ATTN_OFF   101187584u      // f32 [B][M][HW]          524,288
#define ALPHA_OFF  101711872u      // f32 [8]
#define LOSSP_OFF  101712128u      // f32 [256]
#define WREP_OFF   101714176u      // wconv blob              221,184 (8 steps x 1728 granules x 16B)
#define ZPAGE_OFF  101935360u      // 256 B zeros

typedef unsigned short u16;
typedef __attribute__((ext_vector_type(8))) short bf16x8;
typedef __attribute__((ext_vector_type(8))) unsigned short u16x8;
typedef __attribute__((ext_vector_type(4))) float f32x4;

static __device__ __forceinline__ u16 f2bf(float f) {
    unsigned int u = __float_as_uint(f);
    unsigned int r = (u + 0x7FFFu + ((u >> 16) & 1u)) >> 16;
    return (u16)r;
}
static __device__ __forceinline__ float bf2f(u16 h) {
    return __uint_as_float(((unsigned int)h) << 16);
}
static __device__ __forceinline__ float bflo(unsigned int u) {
    return __uint_as_float(u << 16);
}
static __device__ __forceinline__ float bfhi(unsigned int u) {
    return __uint_as_float(u & 0xFFFF0000u);
}

// ---------------- kernel 1: pack X -> channel-last bf16 hi/lo ----------------
__global__ __launch_bounds__(256) void pack_x(const float* __restrict__ Fx,
                                              const float* __restrict__ Fc,
                                              u16* __restrict__ Xt, u16* __restrict__ Xlo) {
    __shared__ float tile[32][33];
    const int blk = blockIdx.x;               // 16384
    const int b = blk >> 11;
    const int rem = blk & 2047;
    const int hw0 = (rem >> 4) << 5;
    const int c0 = (rem & 15) << 5;           // 0..480
    const int tid = threadIdx.x;
    const int ci = tid >> 5, hwi = tid & 31;
#pragma unroll
    for (int it = 0; it < 4; ++it) {
        const int cc = c0 + ci + it * 8;
        const float* src = (cc < 256) ? Fx + (((size_t)b << 8) + cc) * HWc
                                      : Fc + (((size_t)b << 8) + cc - 256) * HWc;
        tile[ci + it * 8][hwi] = src[hw0 + hwi];
    }
    __syncthreads();
    const int pix = tid >> 3, c4 = (tid & 7) << 2;
    const size_t obase = (((size_t)b << 12) + hw0 + pix) * 512 + c0 + c4;
    ushort4 hi4, lo4;
#pragma unroll
    for (int k = 0; k < 4; ++k) {
        const float v = tile[c4 + k][pix];
        const u16 h = f2bf(v);
        ((u16*)&hi4)[k] = h;
        ((u16*)&lo4)[k] = f2bf(v - bf2f(h));
    }
    *(ushort4*)(Xt + obase) = hi4;
    *(ushort4*)(Xlo + obase) = lo4;
}

// ---------------- kernel 2: prep — wfuse cast + wconv swizzled blob + zpage ----------------
__global__ __launch_bounds__(256) void prep(const float* __restrict__ wf,
                                            u16* __restrict__ wbf,
                                            const float* __restrict__ w_off,
                                            const float* __restrict__ w_attn,
                                            u16* __restrict__ wconv,
                                            float* __restrict__ zpage) {
    const int tid = threadIdx.x;
    if (blockIdx.x < 256) {
        const int i = blockIdx.x * 256 + tid;
        const float4 v = *(const float4*)(wf + (size_t)i * 4);
        ushort4 o;
        o.x = f2bf(v.x); o.y = f2bf(v.y); o.z = f2bf(v.z); o.w = f2bf(v.w);
        *(ushort4*)(wbf + (size_t)i * 4) = o;
    } else if (blockIdx.x < 264) {            // EXACTLY 8 steps
        const int step = blockIdx.x - 256;
        for (int n = tid; n < 1728; n += 256) {
            const int par = n & 1;
            const int slot = (n >> 1) & 3;
            const int pair = (n >> 3) % 6;
            const int tap = (n / 48) % 9;
            const int prec = (n / 432) & 1;
            const int sub = n / 864;
            const int oc = pair * 2 + par;
            const int c = slot ^ (pair & 3);
            const int ch = step * 64 + sub * 32 + c * 8;
            u16x8 out;
#pragma unroll
            for (int j = 0; j < 8; ++j) {
                const float v = (oc < 8)
                    ? w_off[((size_t)oc * 512 + ch + j) * 9 + tap]
                    : w_attn[((size_t)(oc - 8) * 512 + ch + j) * 9 + tap];
                const u16 h = f2bf(v);
                out[j] = prec ? f2bf(v - bf2f(h)) : h;
            }
            *(u16x8*)(wconv + ((size_t)step * 1728 + n) * 8) = out;
        }
    } else {
        if (tid < 64) zpage[tid] = 0.f;
    }
}

// ---------------- kernel 3: conv as split-bf16 MFMA implicit GEMM ----------------
#define XBUF_STR 67584
#define XPRC_STR 33792
#define XROW_STR 8448
#define B_BASE   135168
__global__ __launch_bounds__(512) void conv_mfma(
    const u16* __restrict__ Xt, const u16* __restrict__ Xlo,
    const u16* __restrict__ wconv, const float* __restrict__ zpage,
    const float* __restrict__ b_off, const float* __restrict__ b_attn,
    float* __restrict__ dout, float* __restrict__ attnb, float* __restrict__ lossp) {
    __shared__ char smem[163840];

    const int tid = threadIdx.x;
    const int wv = tid >> 6, lane = tid & 63;
    const int gp = wv >> 2, qd = wv & 3;
    const int l15 = lane & 15, g = lane >> 4;
    const int b = blockIdx.x >> 5;
    const int h0 = (blockIdx.x & 31) * 2;
    const int wrow = qd >> 1, wcol0 = (qd & 1) * 32;

    if (tid < 256) {
        const int bu = tid >> 7, pr = (tid >> 6) & 1, rr = (tid >> 4) & 3;
        const int hp = (tid >> 3) & 1, cc = tid & 7;
        const int p = hp ? 65 : 0;
        const float4 z = {0.f, 0.f, 0.f, 0.f};
        *(float4*)(smem + bu * XBUF_STR + pr * XPRC_STR + rr * XROW_STR + p * 128 + cc * 16) = z;
    }

    int pre[2][3];
#pragma unroll
    for (int f = 0; f < 2; ++f)
#pragma unroll
        for (int dx = 0; dx < 3; ++dx) {
            const int p = wcol0 + f * 16 + l15 + dx;      // 0..65
            pre[f][dx] = wrow * XROW_STR + p * 128 + ((((gp << 2) | g) ^ (p & 7)) << 4);
        }
    const int bpair = l15 >> 1, bpar = l15 & 1;
    const int vb = B_BASE + gp * 13824 + bpair * 128 + ((g ^ (bpair & 3)) << 5) + bpar * 16;

    auto stage_X = [&](int step, int buf) {
#pragma unroll
        for (int k = 0; k < 9; ++k) {
            const int f = wv * 9 + k;                     // 0..71
            const int prec = f / 36, rr = (f / 9) & 3, i = f % 9;
            const int p = i * 8 + (lane >> 3);
            const int c = (lane & 7) ^ (p & 7);
            const int col = p - 1;
            const int h = h0 - 1 + rr;
            const bool act = (p >= 1) && (p <= 64);
            const u16* srcb = prec ? Xlo : Xt;
            const char* gsrc = (h >= 0 && h < 64)
                ? (const char*)(srcb + (((size_t)((b << 12) + h * 64 + col)) << 9) + step * 64 + c * 8)
                : (const char*)zpage + ((lane & 7) << 4);
            char* ldst = smem + buf * XBUF_STR + prec * XPRC_STR + rr * XROW_STR + i * 1024;
            if (act)
                __builtin_amdgcn_global_load_lds(
                    (const __attribute__((address_space(1))) unsigned int*)gsrc,
                    (__attribute__((address_space(3))) unsigned int*)ldst, 16, 0, 0);
        }
    };
    auto stage_B = [&](int step) {
        for (int i = wv; i < 27; i += 8) {
            const char* gsrc = (const char*)wconv + (((size_t)step * 1728) + i * 64 + lane) * 16;
            char* ldst = smem + B_BASE + i * 1024;
            __builtin_amdgcn_global_load_lds(
                (const __attribute__((address_space(1))) unsigned int*)gsrc,
                (__attribute__((address_space(3))) unsigned int*)ldst, 16, 0, 0);
        }
    };

    __syncthreads();
    stage_X(0, 0);
    stage_B(0);
    __syncthreads();

    f32x4 acc0 = {}, acc1 = {};

    for (int step = 0; step < 8; ++step) {
        if (step < 7) {
            stage_X(step + 1, (step + 1) & 1);
            asm volatile("s_waitcnt vmcnt(9)" ::: "memory");
        } else {
            asm volatile("s_waitcnt vmcnt(0)" ::: "memory");
        }
        __builtin_amdgcn_s_barrier();
        __builtin_amdgcn_sched_barrier(0);

#pragma unroll
        for (int tap = 0; tap < 9; ++tap) {
            const int dy = tap / 3, dx = tap % 3;
            const bf16x8 bh = *(const bf16x8*)(smem + vb + tap * 768);
            const bf16x8 bl = *(const bf16x8*)(smem + vb + 6912 + tap * 768);
            const bf16x8 a0h = *(const bf16x8*)(smem + pre[0][dx] + dy * XROW_STR);
            const bf16x8 a1h = *(const bf16x8*)(smem + pre[1][dx] + dy * XROW_STR);
            const bf16x8 a0l = *(const bf16x8*)(smem + pre[0][dx] + XPRC_STR + dy * XROW_STR);
            const bf16x8 a1l = *(const bf16x8*)(smem + pre[1][dx] + XPRC_STR + dy * XROW_STR);
            acc0 = __builtin_amdgcn_mfma_f32_16x16x32_bf16(a0h, bh, acc0, 0, 0, 0);
            acc1 = __builtin_amdgcn_mfma_f32_16x16x32_bf16(a1h, bh, acc1, 0, 0, 0);
            acc0 = __builtin_amdgcn_mfma_f32_16x16x32_bf16(a0h, bl, acc0, 0, 0, 0);
            acc1 = __builtin_amdgcn_mfma_f32_16x16x32_bf16(a1h, bl, acc1, 0, 0, 0);
            acc0 = __builtin_amdgcn_mfma_f32_16x16x32_bf16(a0l, bh, acc0, 0, 0, 0);
            acc1 = __builtin_amdgcn_mfma_f32_16x16x32_bf16(a1l, bh, acc1, 0, 0, 0);
        }

        __builtin_amdgcn_sched_barrier(0);
        __builtin_amdgcn_s_barrier();
        __builtin_amdgcn_sched_barrier(0);
        if (step < 7) stage_B(step + 1);
        const int d = (step & 1) ? -XBUF_STR : XBUF_STR;
#pragma unroll
        for (int f = 0; f < 2; ++f)
#pragma unroll
            for (int dx = 0; dx < 3; ++dx) pre[f][dx] += d;
    }

    __syncthreads();
    float* eL = (float*)smem;        // [2 groups][12 oc][128 pix]
    if (l15 < 12) {
#pragma unroll
        for (int r = 0; r < 4; ++r) {
            const int px0 = wrow * 64 + wcol0 + g * 4 + r;
            eL[(gp * 12 + l15) * 128 + px0] = acc0[r];
            eL[(gp * 12 + l15) * 128 + px0 + 16] = acc1[r];
        }
    }
    __syncthreads();
    float labs = 0.f;
    if (tid < 256) {
        const int oc = tid >> 5, seg = tid & 31;
        const float4 v0 = *(const float4*)&eL[oc * 128 + seg * 4];
        const float4 v1 = *(const float4*)&eL[(12 + oc) * 128 + seg * 4];
        const float bo = b_off[oc];
        float4 o;
        o.x = v0.x + v1.x + bo; o.y = v0.y + v1.y + bo;
        o.z = v0.z + v1.z + bo; o.w = v0.w + v1.w + bo;
        *(float4*)(dout + OFFS_BASE + (((size_t)b * 8 + oc) << 12) + h0 * 64 + seg * 4) = o;
        labs = fabsf(o.x) + fabsf(o.y) + fabsf(o.z) + fabsf(o.w);
    } else if (tid < 384) {
        const int t2 = tid - 256;
        const int oc = t2 >> 5, seg = t2 & 31;
        const float4 v0 = *(const float4*)&eL[(8 + oc) * 128 + seg * 4];
        const float4 v1 = *(const float4*)&eL[(20 + oc) * 128 + seg * 4];
        const float ba = b_attn[oc];
        float4 o;
        o.x = 1.f / (1.f + expf(-(v0.x + v1.x + ba)));
        o.y = 1.f / (1.f + expf(-(v0.y + v1.y + ba)));
        o.z = 1.f / (1.f + expf(-(v0.z + v1.z + ba)));
        o.w = 1.f / (1.f + expf(-(v0.w + v1.w + ba)));
        *(float4*)(attnb + (((size_t)b * 4 + oc) << 12) + h0 * 64 + seg * 4) = o;
    }
#pragma unroll
    for (int off = 32; off; off >>= 1) labs += __shfl_down(labs, off);
    float* wr = (float*)(smem + 14336);
    if (lane == 0) wr[wv] = labs;
    __syncthreads();
    if (tid == 0) {
        float s = 0.f;
#pragma unroll
        for (int i = 0; i < 8; ++i) s += wr[i];
        lossp[blockIdx.x] = s;
    }
}

// ---------------- kernel 4: loss reduce + alpha MLP ----------------
__global__ __launch_bounds__(256) void finalize_small(
    const float* __restrict__ lossp, const float* __restrict__ t,
    const float* __restrict__ w1, const float* __restrict__ b1,
    const float* __restrict__ w2, const float* __restrict__ b2,
    float* __restrict__ dout, float* __restrict__ alpha) {
    __shared__ float sd[4];
    const int tid = threadIdx.x;
    float s = lossp[tid];
#pragma unroll
    for (int off = 32; off; off >>= 1) s += __shfl_down(s, off);
    if ((tid & 63) == 0) sd[tid >> 6] = s;
    __syncthreads();
    if (tid == 0) dout[LOSS_IDX] = (sd[0] + sd[1] + sd[2] + sd[3]) * (1.f / 262144.f);

    for (int b = 0; b < 8; ++b) {
        __syncthreads();
        float v = 0.f;
        if (tid < 128) v = fmaxf(fmaf(t[b], w1[tid], b1[tid]), 0.f) * w2[tid];
#pragma unroll
        for (int off = 32; off; off >>= 1) v += __shfl_down(v, off);
        if ((tid & 63) == 0) sd[tid >> 6] = v;
        __syncthreads();
        if (tid == 0) alpha[b] = 1.f / (1.f + expf(-(sd[0] + sd[1] + b2[0])));
    }
}

// ---------------- kernel 5: bilinear gather (bf16) -> head (v2: lean VALU) ----------------
__global__ __launch_bounds__(256) void sample_head(
    const u16* __restrict__ Xt, const float* __restrict__ dout,
    const float* __restrict__ attnb, const float* __restrict__ Wp,
    u16* __restrict__ head) {
    const int tid = threadIdx.x;
    const int wv = tid >> 6, lane = tid & 63;
    const int item = blockIdx.x * 4 + wv;           // (b, m, p)
    const int b = item >> 14;
    const int m = (item >> 12) & 3;
    const int p = item & 4095;
    const int h = p >> 6, wc = p & 63;
    const int hl = lane >> 5, l32 = lane & 31;

    const float off0 = dout[OFFS_BASE + (((size_t)b * 8 + 2 * m) << 12) + p];
    const float off1 = dout[OFFS_BASE + (((size_t)b * 8 + 2 * m + 1) << 12) + p];
    const float a    = attnb[(((size_t)b * 4 + m) << 12) + p];

    const float ysh = -1.f + h * (2.f / 63.f);
    const float xsw = -1.f + wc * (2.f / 63.f);

    const u16* base = Xt + (((size_t)b << 12)) * 512 + 256 + l32 * 8;   // F_c channels
    float acc[8] = {};

#pragma unroll
    for (int r = 0; r < 4; ++r) {
        const float bpy = (r < 2) ? -0.5f : 0.5f;
        const float bpx = (r & 1) ? 0.5f : -0.5f;
        const float c0 = ysh + bpy + off0;   // used as gx (reference quirk)
        const float c1 = xsw + bpx + off1;   // used as gy
        const float ix = (c0 + 1.f) * 31.5f;
        const float iy = (c1 + 1.f) * 31.5f;
        const float x0 = floorf(ix), y0 = floorf(iy);
        const float wx1 = ix - x0, wx0 = 1.f - wx1;
        const float wy1 = iy - y0, wy0 = 1.f - wy1;
        const float xf = x0 + hl;                        // this half-wave's x corner
        const float wxl = (hl ? wx1 : wx0) * (Wp[m * 4 + r] * a);   // attn+Wp folded in
        const bool xin = (xf >= 0.f) && (xf < 64.f);
        const bool v0 = xin && (y0 >= 0.f) && (y0 < 64.f);
        const bool v1 = xin && (y0 >= -1.f) && (y0 < 63.f);
        const int xi = (int)xf;
        // issue both corner loads before the FMA chains
        uint4 u0, u1;
        if (v0) u0 = *(const uint4*)(base + ((size_t)((((int)y0) << 6) + xi)) * 512);
        if (v1) u1 = *(const uint4*)(base + ((size_t)((((int)y0 + 1) << 6) + xi)) * 512);
        if (v0) {
            const float w = wxl * wy0;
            acc[0] = fmaf(w, bflo(u0.x), acc[0]); acc[1] = fmaf(w, bfhi(u0.x), acc[1]);
            acc[2] = fmaf(w, bflo(u0.y), acc[2]); acc[3] = fmaf(w, bfhi(u0.y), acc[3]);
            acc[4] = fmaf(w, bflo(u0.z), acc[4]); acc[5] = fmaf(w, bfhi(u0.z), acc[5]);
            acc[6] = fmaf(w, bflo(u0.w), acc[6]); acc[7] = fmaf(w, bfhi(u0.w), acc[7]);
        }
        if (v1) {
            const float w = wxl * wy1;
            acc[0] = fmaf(w, bflo(u1.x), acc[0]); acc[1] = fmaf(w, bfhi(u1.x), acc[1]);
            acc[2] = fmaf(w, bflo(u1.y), acc[2]); acc[3] = fmaf(w, bfhi(u1.y), acc[3]);
            acc[4] = fmaf(w, bflo(u1.z), acc[4]); acc[5] = fmaf(w, bfhi(u1.z), acc[5]);
            acc[6] = fmaf(w, bflo(u1.w), acc[6]); acc[7] = fmaf(w, bfhi(u1.w), acc[7]);
        }
    }
#pragma unroll
    for (int j = 0; j < 8; ++j) acc[j] += __shfl_xor(acc[j], 32);
    if (lane < 32) {
        u16x8 o;
#pragma unroll
        for (int j = 0; j < 8; ++j) o[j] = f2bf(acc[j]);
        *(u16x8*)(head + (((size_t)b << 12) + p) * KDIM + m * 256 + l32 * 8) = o;
    }
}

// ---------------- kernel 6: fuse GEMM (bf16 MFMA) + blend epilogue (round-1 proven) ----------------
__global__ __launch_bounds__(256) void fuse_gemm(
    const u16* __restrict__ head, const u16* __restrict__ wbf,
    const float* __restrict__ Fx, const float* __restrict__ bfuse,
    const float* __restrict__ alpha, float* __restrict__ dout) {
    __shared__ u16 Asl[128 * 32];   // [row(pix)][k]
    __shared__ u16 Bsl[128 * 32];   // [col(co)][k]

    const int tid = threadIdx.x;
    const int lane = tid & 63, wv = tid >> 6;
    const int wm = wv >> 1, wn = wv & 1;
    const int l15 = lane & 15, g = lane >> 4;
    const size_t arow0 = (size_t)blockIdx.x * 128;
    const int co0 = blockIdx.y * 128;

    f32x4 acc[4][4] = {};

    const int row0 = tid >> 2, kc0 = (tid & 3) * 8;
    const int row1 = (tid + 256) >> 2, kc1 = ((tid + 256) & 3) * 8;

    for (int kt = 0; kt < 32; ++kt) {
        const int k0 = kt * 32;
        uint4 a0 = *(const uint4*)(head + (arow0 + row0) * KDIM + k0 + kc0);
        uint4 b0 = *(const uint4*)(wbf + (size_t)(co0 + row0) * KDIM + k0 + kc0);
        uint4 a1 = *(const uint4*)(head + (arow0 + row1) * KDIM + k0 + kc1);
        uint4 b1 = *(const uint4*)(wbf + (size_t)(co0 + row1) * KDIM + k0 + kc1);
        __syncthreads();
        *(uint4*)&Asl[tid * 8] = a0;
        *(uint4*)&Asl[(tid + 256) * 8] = a1;
        *(uint4*)&Bsl[tid * 8] = b0;
        *(uint4*)&Bsl[(tid + 256) * 8] = b1;
        __syncthreads();

        bf16x8 af[4], bf[4];
#pragma unroll
        for (int f = 0; f < 4; ++f) {
            af[f] = *(const bf16x8*)&Asl[(wm * 64 + f * 16 + l15) * 32 + g * 8];
            bf[f] = *(const bf16x8*)&Bsl[(wn * 64 + f * 16 + l15) * 32 + g * 8];
        }
#pragma unroll
        for (int i = 0; i < 4; ++i)
#pragma unroll
            for (int j = 0; j < 4; ++j)
                acc[i][j] = __builtin_amdgcn_mfma_f32_16x16x32_bf16(af[i], bf[j], acc[i][j], 0, 0, 0);
    }

    const int b = (int)(arow0 >> 12);
    const float al = alpha[b], il = 1.f - al;
    const int pixbase = (int)(arow0 & 4095);
#pragma unroll
    for (int i = 0; i < 4; ++i) {
        const int rowl = wm * 64 + i * 16 + g * 4;
        const int pix = pixbase + rowl;
#pragma unroll
        for (int j = 0; j < 4; ++j) {
            const int co = co0 + wn * 64 + j * 16 + l15;
            const float bias = bfuse[co];
            const size_t idx = (((size_t)b << 8) + co) * HWc + pix;
            const float4 fx = *(const float4*)(Fx + idx);
            const f32x4 v = acc[i][j];
            float4 o;
            o.x = al * (v[0] + bias) + il * fx.x;
            o.y = al * (v[1] + bias) + il * fx.y;
            o.z = al * (v[2] + bias) + il * fx.z;
            o.w = al * (v[3] + bias) + il * fx.w;
            *(float4*)(dout + idx) = o;
        }
    }
}

// ---------------- launcher ----------------
extern "C" void kernel_launch(void* const* d_in, const int* in_sizes, int n_in,
                              void* d_out, int out_size, void* d_ws, size_t ws_size,
                              hipStream_t stream) {
    const float* F_x    = (const float*)d_in[0];
    const float* F_c    = (const float*)d_in[1];
    const float* t      = (const float*)d_in[2];
    const float* w_off  = (const float*)d_in[3];
    const float* b_off  = (const float*)d_in[4];
    const float* w_attn = (const float*)d_in[5];
    const float* b_attn = (const float*)d_in[6];
    const float* Wp     = (const float*)d_in[7];
    const float* w_fuse = (const float*)d_in[8];
    const float* b_fuse = (const float*)d_in[9];
    const float* w1     = (const float*)d_in[10];
    const float* b1     = (const float*)d_in[11];
    const float* w2     = (const float*)d_in[12];
    const float* b2     = (const float*)d_in[13];
    float* out = (float*)d_out;

    char* ws = (char*)d_ws;
    u16*   Xt    = (u16*)(ws + XT_OFF);
    u16*   Xlo   = (u16*)(ws + HEAD_OFF);     // aliases head (conv finishes first)
    u16*   head  = (u16*)(ws + HEAD_OFF);
    u16*   wbf   = (u16*)(ws + WBF_OFF);
    float* attnb = (float*)(ws + ATTN_OFF);
    float* alphb = (float*)(ws + ALPHA_OFF);
    float* lossp = (float*)(ws + LOSSP_OFF);
    u16*   wconv = (u16*)(ws + WREP_OFF);
    float* zpage = (float*)(ws + ZPAGE_OFF);

    pack_x<<<dim3(16384), dim3(256), 0, stream>>>(F_x, F_c, Xt, Xlo);
    prep<<<dim3(265), dim3(256), 0, stream>>>(w_fuse, wbf, w_off, w_attn, wconv, zpage);
    conv_mfma<<<dim3(256), dim3(512), 0, stream>>>(Xt, Xlo, wconv, zpage, b_off, b_attn,
                                                   out, attnb, lossp);
    finalize_small<<<dim3(1), dim3(256), 0, stream>>>(lossp, t, w1, b1, w2, b2, out, alphb);
    sample_head<<<dim3(32768), dim3(256), 0, stream>>>(Xt, out, attnb, Wp, head);
    fuse_gemm<<<dim3(256, 2), dim3(256), 0, stream>>>(head, wbf, F_x, b_fuse, alphb, out);
}

// Round 10
// 137.215 us; speedup vs baseline: 1.1405x; 1.0278x over previous
//
#include <hip/hip_runtime.h>
#include <hip/hip_bf16.h>

// ---------------- problem constants ----------------
#define Bc   8
#define Cc   256
#define Hc   64
#define Wc   64
#define HWc  4096
#define KDIM 1024          // M*C

#define LOSS_IDX   8388608
#define OFFS_BASE  8388609        // offsets output base in d_out

// ---------------- ws layout (bytes) ----------------
#define XT_OFF     0u              // bf16 [B][HW][512] hi   33,554,432
#define HEAD_OFF   33554432u       // Xlo bf16 (conv) THEN head bf16 [NROW][KDIM] (tail)
#define WBF_OFF    100663296u      // bf16 [C][KDIM]          524,288
#define ATTN_OFF   101187584u      // f32 [B][M][HW]          524,288
#define ALPHA_OFF  101711872u      // f32 [8]
#define LOSSP_OFF  101712128u      // f32 [256]
#define WREP_OFF   101714176u      // wconv blob              221,184 (8 steps x 1728 granules x 16B)
#define ZPAGE_OFF  101935360u      // 256 B zeros

typedef unsigned short u16;
typedef __attribute__((ext_vector_type(8))) short bf16x8;
typedef __attribute__((ext_vector_type(8))) unsigned short u16x8;
typedef __attribute__((ext_vector_type(4))) float f32x4;

static __device__ __forceinline__ u16 f2bf(float f) {
    unsigned int u = __float_as_uint(f);
    unsigned int r = (u + 0x7FFFu + ((u >> 16) & 1u)) >> 16;
    return (u16)r;
}
static __device__ __forceinline__ float bf2f(u16 h) {
    return __uint_as_float(((unsigned int)h) << 16);
}
static __device__ __forceinline__ float bflo(unsigned int u) {
    return __uint_as_float(u << 16);
}
static __device__ __forceinline__ float bfhi(unsigned int u) {
    return __uint_as_float(u & 0xFFFF0000u);
}

// ---------------- kernel 1: pack X -> channel-last bf16 hi/lo ----------------
__global__ __launch_bounds__(256) void pack_x(const float* __restrict__ Fx,
                                              const float* __restrict__ Fc,
                                              u16* __restrict__ Xt, u16* __restrict__ Xlo) {
    __shared__ float tile[32][33];
    const int blk = blockIdx.x;               // 16384
    const int b = blk >> 11;
    const int rem = blk & 2047;
    const int hw0 = (rem >> 4) << 5;
    const int c0 = (rem & 15) << 5;           // 0..480
    const int tid = threadIdx.x;
    const int ci = tid >> 5, hwi = tid & 31;
#pragma unroll
    for (int it = 0; it < 4; ++it) {
        const int cc = c0 + ci + it * 8;
        const float* src = (cc < 256) ? Fx + (((size_t)b << 8) + cc) * HWc
                                      : Fc + (((size_t)b << 8) + cc - 256) * HWc;
        tile[ci + it * 8][hwi] = src[hw0 + hwi];
    }
    __syncthreads();
    const int pix = tid >> 3, c4 = (tid & 7) << 2;
    const size_t obase = (((size_t)b << 12) + hw0 + pix) * 512 + c0 + c4;
    ushort4 hi4, lo4;
#pragma unroll
    for (int k = 0; k < 4; ++k) {
        const float v = tile[c4 + k][pix];
        const u16 h = f2bf(v);
        ((u16*)&hi4)[k] = h;
        ((u16*)&lo4)[k] = f2bf(v - bf2f(h));
    }
    *(ushort4*)(Xt + obase) = hi4;
    *(ushort4*)(Xlo + obase) = lo4;
}

// ---------------- kernel 2: prep — wfuse cast + wconv swizzled blob + zpage ----------------
__global__ __launch_bounds__(256) void prep(const float* __restrict__ wf,
                                            u16* __restrict__ wbf,
                                            const float* __restrict__ w_off,
                                            const float* __restrict__ w_attn,
                                            u16* __restrict__ wconv,
                                            float* __restrict__ zpage) {
    const int tid = threadIdx.x;
    if (blockIdx.x < 256) {
        const int i = blockIdx.x * 256 + tid;
        const float4 v = *(const float4*)(wf + (size_t)i * 4);
        ushort4 o;
        o.x = f2bf(v.x); o.y = f2bf(v.y); o.z = f2bf(v.z); o.w = f2bf(v.w);
        *(ushort4*)(wbf + (size_t)i * 4) = o;
    } else if (blockIdx.x < 264) {            // EXACTLY 8 steps
        const int step = blockIdx.x - 256;
        for (int n = tid; n < 1728; n += 256) {
            const int par = n & 1;
            const int slot = (n >> 1) & 3;
            const int pair = (n >> 3) % 6;
            const int tap = (n / 48) % 9;
            const int prec = (n / 432) & 1;
            const int sub = n / 864;
            const int oc = pair * 2 + par;
            const int c = slot ^ (pair & 3);
            const int ch = step * 64 + sub * 32 + c * 8;
            u16x8 out;
#pragma unroll
            for (int j = 0; j < 8; ++j) {
                const float v = (oc < 8)
                    ? w_off[((size_t)oc * 512 + ch + j) * 9 + tap]
                    : w_attn[((size_t)(oc - 8) * 512 + ch + j) * 9 + tap];
                const u16 h = f2bf(v);
                out[j] = prec ? f2bf(v - bf2f(h)) : h;
            }
            *(u16x8*)(wconv + ((size_t)step * 1728 + n) * 8) = out;
        }
    } else {
        if (tid < 64) zpage[tid] = 0.f;
    }
}

// ---------------- kernel 3: conv as split-bf16 MFMA implicit GEMM ----------------
#define XBUF_STR 67584
#define XPRC_STR 33792
#define XROW_STR 8448
#define B_BASE   135168
__global__ __launch_bounds__(512) void conv_mfma(
    const u16* __restrict__ Xt, const u16* __restrict__ Xlo,
    const u16* __restrict__ wconv, const float* __restrict__ zpage,
    const float* __restrict__ b_off, const float* __restrict__ b_attn,
    float* __restrict__ dout, float* __restrict__ attnb, float* __restrict__ lossp) {
    __shared__ char smem[163840];

    const int tid = threadIdx.x;
    const int wv = tid >> 6, lane = tid & 63;
    const int gp = wv >> 2, qd = wv & 3;
    const int l15 = lane & 15, g = lane >> 4;
    const int b = blockIdx.x >> 5;
    const int h0 = (blockIdx.x & 31) * 2;
    const int wrow = qd >> 1, wcol0 = (qd & 1) * 32;

    if (tid < 256) {
        const int bu = tid >> 7, pr = (tid >> 6) & 1, rr = (tid >> 4) & 3;
        const int hp = (tid >> 3) & 1, cc = tid & 7;
        const int p = hp ? 65 : 0;
        const float4 z = {0.f, 0.f, 0.f, 0.f};
        *(float4*)(smem + bu * XBUF_STR + pr * XPRC_STR + rr * XROW_STR + p * 128 + cc * 16) = z;
    }

    int pre[2][3];
#pragma unroll
    for (int f = 0; f < 2; ++f)
#pragma unroll
        for (int dx = 0; dx < 3; ++dx) {
            const int p = wcol0 + f * 16 + l15 + dx;      // 0..65
            pre[f][dx] = wrow * XROW_STR + p * 128 + ((((gp << 2) | g) ^ (p & 7)) << 4);
        }
    const int bpair = l15 >> 1, bpar = l15 & 1;
    const int vb = B_BASE + gp * 13824 + bpair * 128 + ((g ^ (bpair & 3)) << 5) + bpar * 16;

    auto stage_X = [&](int step, int buf) {
#pragma unroll
        for (int k = 0; k < 9; ++k) {
            const int f = wv * 9 + k;                     // 0..71
            const int prec = f / 36, rr = (f / 9) & 3, i = f % 9;
            const int p = i * 8 + (lane >> 3);
            const int c = (lane & 7) ^ (p & 7);
            const int col = p - 1;
            const int h = h0 - 1 + rr;
            const bool act = (p >= 1) && (p <= 64);
            const u16* srcb = prec ? Xlo : Xt;
            const char* gsrc = (h >= 0 && h < 64)
                ? (const char*)(srcb + (((size_t)((b << 12) + h * 64 + col)) << 9) + step * 64 + c * 8)
                : (const char*)zpage + ((lane & 7) << 4);
            char* ldst = smem + buf * XBUF_STR + prec * XPRC_STR + rr * XROW_STR + i * 1024;
            if (act)
                __builtin_amdgcn_global_load_lds(
                    (const __attribute__((address_space(1))) unsigned int*)gsrc,
                    (__attribute__((address_space(3))) unsigned int*)ldst, 16, 0, 0);
        }
    };
    auto stage_B = [&](int step) {
        for (int i = wv; i < 27; i += 8) {
            const char* gsrc = (const char*)wconv + (((size_t)step * 1728) + i * 64 + lane) * 16;
            char* ldst = smem + B_BASE + i * 1024;
            __builtin_amdgcn_global_load_lds(
                (const __attribute__((address_space(1))) unsigned int*)gsrc,
                (__attribute__((address_space(3))) unsigned int*)ldst, 16, 0, 0);
        }
    };

    __syncthreads();
    stage_X(0, 0);
    stage_B(0);
    __syncthreads();

    f32x4 acc0 = {}, acc1 = {};

    for (int step = 0; step < 8; ++step) {
        if (step < 7) {
            stage_X(step + 1, (step + 1) & 1);
            asm volatile("s_waitcnt vmcnt(9)" ::: "memory");
        } else {
            asm volatile("s_waitcnt vmcnt(0)" ::: "memory");
        }
        __builtin_amdgcn_s_barrier();
        __builtin_amdgcn_sched_barrier(0);

#pragma unroll
        for (int tap = 0; tap < 9; ++tap) {
            const int dy = tap / 3, dx = tap % 3;
            const bf16x8 bh = *(const bf16x8*)(smem + vb + tap * 768);
            const bf16x8 bl = *(const bf16x8*)(smem + vb + 6912 + tap * 768);
            const bf16x8 a0h = *(const bf16x8*)(smem + pre[0][dx] + dy * XROW_STR);
            const bf16x8 a1h = *(const bf16x8*)(smem + pre[1][dx] + dy * XROW_STR);
            const bf16x8 a0l = *(const bf16x8*)(smem + pre[0][dx] + XPRC_STR + dy * XROW_STR);
            const bf16x8 a1l = *(const bf16x8*)(smem + pre[1][dx] + XPRC_STR + dy * XROW_STR);
            acc0 = __builtin_amdgcn_mfma_f32_16x16x32_bf16(a0h, bh, acc0, 0, 0, 0);
            acc1 = __builtin_amdgcn_mfma_f32_16x16x32_bf16(a1h, bh, acc1, 0, 0, 0);
            acc0 = __builtin_amdgcn_mfma_f32_16x16x32_bf16(a0h, bl, acc0, 0, 0, 0);
            acc1 = __builtin_amdgcn_mfma_f32_16x16x32_bf16(a1h, bl, acc1, 0, 0, 0);
            acc0 = __builtin_amdgcn_mfma_f32_16x16x32_bf16(a0l, bh, acc0, 0, 0, 0);
            acc1 = __builtin_amdgcn_mfma_f32_16x16x32_bf16(a1l, bh, acc1, 0, 0, 0);
        }

        __builtin_amdgcn_sched_barrier(0);
        __builtin_amdgcn_s_barrier();
        __builtin_amdgcn_sched_barrier(0);
        if (step < 7) stage_B(step + 1);
        const int d = (step & 1) ? -XBUF_STR : XBUF_STR;
#pragma unroll
        for (int f = 0; f < 2; ++f)
#pragma unroll
            for (int dx = 0; dx < 3; ++dx) pre[f][dx] += d;
    }

    __syncthreads();
    float* eL = (float*)smem;        // [2 groups][12 oc][128 pix]
    if (l15 < 12) {
#pragma unroll
        for (int r = 0; r < 4; ++r) {
            const int px0 = wrow * 64 + wcol0 + g * 4 + r;
            eL[(gp * 12 + l15) * 128 + px0] = acc0[r];
            eL[(gp * 12 + l15) * 128 + px0 + 16] = acc1[r];
        }
    }
    __syncthreads();
    float labs = 0.f;
    if (tid < 256) {
        const int oc = tid >> 5, seg = tid & 31;
        const float4 v0 = *(const float4*)&eL[oc * 128 + seg * 4];
        const float4 v1 = *(const float4*)&eL[(12 + oc) * 128 + seg * 4];
        const float bo = b_off[oc];
        float4 o;
        o.x = v0.x + v1.x + bo; o.y = v0.y + v1.y + bo;
        o.z = v0.z + v1.z + bo; o.w = v0.w + v1.w + bo;
        *(float4*)(dout + OFFS_BASE + (((size_t)b * 8 + oc) << 12) + h0 * 64 + seg * 4) = o;
        labs = fabsf(o.x) + fabsf(o.y) + fabsf(o.z) + fabsf(o.w);
    } else if (tid < 384) {
        const int t2 = tid - 256;
        const int oc = t2 >> 5, seg = t2 & 31;
        const float4 v0 = *(const float4*)&eL[(8 + oc) * 128 + seg * 4];
        const float4 v1 = *(const float4*)&eL[(20 + oc) * 128 + seg * 4];
        const float ba = b_attn[oc];
        float4 o;
        o.x = 1.f / (1.f + expf(-(v0.x + v1.x + ba)));
        o.y = 1.f / (1.f + expf(-(v0.y + v1.y + ba)));
        o.z = 1.f / (1.f + expf(-(v0.z + v1.z + ba)));
        o.w = 1.f / (1.f + expf(-(v0.w + v1.w + ba)));
        *(float4*)(attnb + (((size_t)b * 4 + oc) << 12) + h0 * 64 + seg * 4) = o;
    }
#pragma unroll
    for (int off = 32; off; off >>= 1) labs += __shfl_down(labs, off);
    float* wr = (float*)(smem + 14336);
    if (lane == 0) wr[wv] = labs;
    __syncthreads();
    if (tid == 0) {
        float s = 0.f;
#pragma unroll
        for (int i = 0; i < 8; ++i) s += wr[i];
        lossp[blockIdx.x] = s;
    }
}

// ---------------- kernel 4: loss reduce + alpha MLP ----------------
__global__ __launch_bounds__(256) void finalize_small(
    const float* __restrict__ lossp, const float* __restrict__ t,
    const float* __restrict__ w1, const float* __restrict__ b1,
    const float* __restrict__ w2, const float* __restrict__ b2,
    float* __restrict__ dout, float* __restrict__ alpha) {
    __shared__ float sd[4];
    const int tid = threadIdx.x;
    float s = lossp[tid];
#pragma unroll
    for (int off = 32; off; off >>= 1) s += __shfl_down(s, off);
    if ((tid & 63) == 0) sd[tid >> 6] = s;
    __syncthreads();
    if (tid == 0) dout[LOSS_IDX] = (sd[0] + sd[1] + sd[2] + sd[3]) * (1.f / 262144.f);

    for (int b = 0; b < 8; ++b) {
        __syncthreads();
        float v = 0.f;
        if (tid < 128) v = fmaxf(fmaf(t[b], w1[tid], b1[tid]), 0.f) * w2[tid];
#pragma unroll
        for (int off = 32; off; off >>= 1) v += __shfl_down(v, off);
        if ((tid & 63) == 0) sd[tid >> 6] = v;
        __syncthreads();
        if (tid == 0) alpha[b] = 1.f / (1.f + expf(-(sd[0] + sd[1] + b2[0])));
    }
}

// ---------------- kernel 5: bilinear gather (bf16) -> head ----------------
__global__ __launch_bounds__(256) void sample_head(
    const u16* __restrict__ Xt, const float* __restrict__ dout,
    const float* __restrict__ attnb, const float* __restrict__ Wp,
    u16* __restrict__ head) {
    const int tid = threadIdx.x;
    const int wv = tid >> 6, lane = tid & 63;
    const int item = blockIdx.x * 4 + wv;           // (b, m, p)
    const int b = item >> 14;
    const int m = (item >> 12) & 3;
    const int p = item & 4095;
    const int h = p >> 6, wc = p & 63;
    const int hl = lane >> 5, l32 = lane & 31;

    const float off0 = dout[OFFS_BASE + (((size_t)b * 8 + 2 * m) << 12) + p];
    const float off1 = dout[OFFS_BASE + (((size_t)b * 8 + 2 * m + 1) << 12) + p];
    const float a    = attnb[(((size_t)b * 4 + m) << 12) + p];

    const float ysh = -1.f + h * (2.f / 63.f);
    const float xsw = -1.f + wc * (2.f / 63.f);

    const u16* base = Xt + (((size_t)b << 12)) * 512 + 256 + l32 * 8;   // F_c channels
    float acc[8] = {};

#pragma unroll
    for (int r = 0; r < 4; ++r) {
        const float bpy = (r < 2) ? -0.5f : 0.5f;
        const float bpx = (r & 1) ? 0.5f : -0.5f;
        const float c0 = ysh + bpy + off0;   // used as gx (reference quirk)
        const float c1 = xsw + bpx + off1;   // used as gy
        const float ix = (c0 + 1.f) * 31.5f;
        const float iy = (c1 + 1.f) * 31.5f;
        const float x0 = floorf(ix), y0 = floorf(iy);
        const float wx1 = ix - x0, wx0 = 1.f - wx1;
        const float wy1 = iy - y0, wy0 = 1.f - wy1;
        const float xf = x0 + hl;                        // this half-wave's x corner
        const float wxl = (hl ? wx1 : wx0) * (Wp[m * 4 + r] * a);   // attn+Wp folded in
        const bool xin = (xf >= 0.f) && (xf < 64.f);
        const bool v0 = xin && (y0 >= 0.f) && (y0 < 64.f);
        const bool v1 = xin && (y0 >= -1.f) && (y0 < 63.f);
        const int xi = (int)xf;
        uint4 u0, u1;
        if (v0) u0 = *(const uint4*)(base + ((size_t)((((int)y0) << 6) + xi)) * 512);
        if (v1) u1 = *(const uint4*)(base + ((size_t)((((int)y0 + 1) << 6) + xi)) * 512);
        if (v0) {
            const float w = wxl * wy0;
            acc[0] = fmaf(w, bflo(u0.x), acc[0]); acc[1] = fmaf(w, bfhi(u0.x), acc[1]);
            acc[2] = fmaf(w, bflo(u0.y), acc[2]); acc[3] = fmaf(w, bfhi(u0.y), acc[3]);
            acc[4] = fmaf(w, bflo(u0.z), acc[4]); acc[5] = fmaf(w, bfhi(u0.z), acc[5]);
            acc[6] = fmaf(w, bflo(u0.w), acc[6]); acc[7] = fmaf(w, bfhi(u0.w), acc[7]);
        }
        if (v1) {
            const float w = wxl * wy1;
            acc[0] = fmaf(w, bflo(u1.x), acc[0]); acc[1] = fmaf(w, bfhi(u1.x), acc[1]);
            acc[2] = fmaf(w, bflo(u1.y), acc[2]); acc[3] = fmaf(w, bfhi(u1.y), acc[3]);
            acc[4] = fmaf(w, bflo(u1.z), acc[4]); acc[5] = fmaf(w, bfhi(u1.z), acc[5]);
            acc[6] = fmaf(w, bflo(u1.w), acc[6]); acc[7] = fmaf(w, bfhi(u1.w), acc[7]);
        }
    }
#pragma unroll
    for (int j = 0; j < 8; ++j) acc[j] += __shfl_xor(acc[j], 32);
    if (lane < 32) {
        u16x8 o;
#pragma unroll
        for (int j = 0; j < 8; ++j) o[j] = f2bf(acc[j]);
        *(u16x8*)(head + (((size_t)b << 12) + p) * KDIM + m * 256 + l32 * 8) = o;
    }
}

// ---------------- kernel 6: fuse GEMM v3 — global_load_lds + XOR-swizzle (conflict-free) ----------------
// LDS per matrix per buffer: [128 rows][64 B] with 16B chunk slot s holding global
// k-chunk s ^ ((row>>1)&3). DMA: linear LDS dest + pre-swizzled per-lane global src (m173).
__global__ __launch_bounds__(256) void fuse_gemm(
    const u16* __restrict__ head, const u16* __restrict__ wbf,
    const float* __restrict__ Fx, const float* __restrict__ bfuse,
    const float* __restrict__ alpha, float* __restrict__ dout) {
    __shared__ __attribute__((aligned(16))) char smem[2][2][8192];   // [buf][A/B][128*64]

    const int tid = threadIdx.x;
    const int lane = tid & 63, wv = tid >> 6;
    const int wm = wv >> 1, wn = wv & 1;
    const int l15 = lane & 15, g = lane >> 4;
    const size_t arow0 = (size_t)blockIdx.x * 128;
    const int co0 = blockIdx.y * 128;

    f32x4 acc[4][4] = {};

    // staging: waves 0,1 -> A halves; waves 2,3 -> B halves. 4 instrs/wave/tile.
    const int isB = wv >> 1;
    const int half = wv & 1;
    const u16* srcbase = isB ? wbf + (size_t)co0 * KDIM : head + arow0 * KDIM;
    const int lrow = half * 64 + (lane >> 2);        // + i*16 per instr
    const int lslot = lane & 3;

    auto stage = [&](int kt, int buf) {
#pragma unroll
        for (int i = 0; i < 4; ++i) {
            const int row = lrow + i * 16;
            const int gc = lslot ^ ((row >> 1) & 3);            // global k-chunk
            const u16* gsrc = srcbase + (size_t)row * KDIM + kt * 32 + gc * 8;
            char* ldst = smem[buf][isB] + (half * 64 + i * 16) * 64;
            __builtin_amdgcn_global_load_lds(
                (const __attribute__((address_space(1))) unsigned int*)gsrc,
                (__attribute__((address_space(3))) unsigned int*)ldst, 16, 0, 0);
        }
    };

    stage(0, 0);
    __syncthreads();

    for (int kt = 0; kt < 32; ++kt) {
        if (kt < 31) {
            stage(kt + 1, (kt + 1) & 1);
            asm volatile("s_waitcnt vmcnt(4)" ::: "memory");   // tile kt's 4 loads done
        } else {
            asm volatile("s_waitcnt vmcnt(0)" ::: "memory");
        }
        __builtin_amdgcn_s_barrier();
        __builtin_amdgcn_sched_barrier(0);

        const char* Ab = smem[kt & 1][0];
        const char* Bb = smem[kt & 1][1];
        bf16x8 af[4], bf[4];
#pragma unroll
        for (int f = 0; f < 4; ++f) {
            const int ra = wm * 64 + f * 16 + l15;
            const int rb = wn * 64 + f * 16 + l15;
            af[f] = *(const bf16x8*)(Ab + ra * 64 + ((g ^ ((ra >> 1) & 3)) << 4));
            bf[f] = *(const bf16x8*)(Bb + rb * 64 + ((g ^ ((rb >> 1) & 3)) << 4));
        }
#pragma unroll
        for (int i = 0; i < 4; ++i)
#pragma unroll
            for (int j = 0; j < 4; ++j)
                acc[i][j] = __builtin_amdgcn_mfma_f32_16x16x32_bf16(af[i], bf[j], acc[i][j], 0, 0, 0);

        __builtin_amdgcn_sched_barrier(0);
        __builtin_amdgcn_s_barrier();       // all waves done reading before next overwrite
        __builtin_amdgcn_sched_barrier(0);
    }

    const int b = (int)(arow0 >> 12);
    const float al = alpha[b], il = 1.f - al;
    const int pixbase = (int)(arow0 & 4095);
#pragma unroll
    for (int i = 0; i < 4; ++i) {
        const int rowl = wm * 64 + i * 16 + g * 4;
        const int pix = pixbase + rowl;
#pragma unroll
        for (int j = 0; j < 4; ++j) {
            const int co = co0 + wn * 64 + j * 16 + l15;
            const float bias = bfuse[co];
            const size_t idx = (((size_t)b << 8) + co) * HWc + pix;
            const float4 fx = *(const float4*)(Fx + idx);
            const f32x4 v = acc[i][j];
            float4 o;
            o.x = al * (v[0] + bias) + il * fx.x;
            o.y = al * (v[1] + bias) + il * fx.y;
            o.z = al * (v[2] + bias) + il * fx.z;
            o.w = al * (v[3] + bias) + il * fx.w;
            *(float4*)(dout + idx) = o;
        }
    }
}

// ---------------- launcher ----------------
extern "C" void kernel_launch(void* const* d_in, const int* in_sizes, int n_in,
                              void* d_out, int out_size, void* d_ws, size_t ws_size,
                              hipStream_t stream) {
    const float* F_x    = (const float*)d_in[0];
    const float* F_c    = (const float*)d_in[1];
    const float* t      = (const float*)d_in[2];
    const float* w_off  = (const float*)d_in[3];
    const float* b_off  = (const float*)d_in[4];
    const float* w_attn = (const float*)d_in[5];
    const float* b_attn = (const float*)d_in[6];
    const float* Wp     = (const float*)d_in[7];
    const float* w_fuse = (const float*)d_in[8];
    const float* b_fuse = (const float*)d_in[9];
    const float* w1     = (const float*)d_in[10];
    const float* b1     = (const float*)d_in[11];
    const float* w2     = (const float*)d_in[12];
    const float* b2     = (const float*)d_in[13];
    float* out = (float*)d_out;

    char* ws = (char*)d_ws;
    u16*   Xt    = (u16*)(ws + XT_OFF);
    u16*   Xlo   = (u16*)(ws + HEAD_OFF);     // aliases head (conv finishes first)
    u16*   head  = (u16*)(ws + HEAD_OFF);
    u16*   wbf   = (u16*)(ws + WBF_OFF);
    float* attnb = (float*)(ws + ATTN_OFF);
    float* alphb = (float*)(ws + ALPHA_OFF);
    float* lossp = (float*)(ws + LOSSP_OFF);
    u16*   wconv = (u16*)(ws + WREP_OFF);
    float* zpage = (float*)(ws + ZPAGE_OFF);

    pack_x<<<dim3(16384), dim3(256), 0, stream>>>(F_x, F_c, Xt, Xlo);
    prep<<<dim3(265), dim3(256), 0, stream>>>(w_fuse, wbf, w_off, w_attn, wconv, zpage);
    conv_mfma<<<dim3(256), dim3(512), 0, stream>>>(Xt, Xlo, wconv, zpage, b_off, b_attn,
                                                   out, attnb, lossp);
    finalize_small<<<dim3(1), dim3(256), 0, stream>>>(lossp, t, w1, b1, w2, b2, out, alphb);
    sample_head<<<dim3(32768), dim3(256), 0, stream>>>(Xt, out, attnb, Wp, head);
    fuse_gemm<<<dim3(256, 2), dim3(256), 0, stream>>>(head, wbf, F_x, b_fuse, alphb, out);
}

// Round 11
// 126.536 us; speedup vs baseline: 1.2368x; 1.0844x over previous
//
#include <hip/hip_runtime.h>
#include <hip/hip_bf16.h>

// ---------------- problem constants ----------------
#define Bc   8
#define Cc   256
#define Hc   64
#define Wc   64
#define HWc  4096
#define KDIM 1024          // M*C

#define LOSS_IDX   8388608
#define OFFS_BASE  8388609        // offsets output base in d_out

// ---------------- ws layout (bytes) ----------------
#define XT_OFF     0u              // bf16 [B][HW][512] hi   33,554,432
#define HEAD_OFF   33554432u       // Xlo bf16 (conv) THEN head fp8 [NROW][KDIM] (tail, 32MB)
#define XF8_OFF    67108864u       // fp8 [B][HW][256] F_c    8,388,608
#define WBF_OFF    100663296u      // fp8 [C][KDIM]           262,144
#define ATTN_OFF   101187584u      // f32 [B][M][HW]          524,288
#define ALPHA_OFF  101711872u      // f32 [8]
#define LOSSP_OFF  101712128u      // f32 [256]
#define WREP_OFF   101714176u      // wconv blob              221,184 (8 steps x 1728 granules x 16B)
#define ZPAGE_OFF  101935360u      // 256 B zeros

typedef unsigned short u16;
typedef unsigned char u8;
typedef __attribute__((ext_vector_type(8))) short bf16x8;
typedef __attribute__((ext_vector_type(8))) unsigned short u16x8;
typedef __attribute__((ext_vector_type(4))) float f32x4;
typedef __attribute__((ext_vector_type(2))) float f32x2;

static __device__ __forceinline__ u16 f2bf(float f) {
    unsigned int u = __float_as_uint(f);
    unsigned int r = (u + 0x7FFFu + ((u >> 16) & 1u)) >> 16;
    return (u16)r;
}
static __device__ __forceinline__ float bf2f(u16 h) {
    return __uint_as_float(((unsigned int)h) << 16);
}
static __device__ __forceinline__ unsigned int pk4_fp8(float a, float b, float c, float d) {
    int r = __builtin_amdgcn_cvt_pk_fp8_f32(a, b, 0, false);
    r = __builtin_amdgcn_cvt_pk_fp8_f32(c, d, r, true);
    return (unsigned int)r;
}

// ---------------- kernel 1: pack X -> channel-last bf16 hi/lo (+ fp8 F_c) ----------------
__global__ __launch_bounds__(256) void pack_x(const float* __restrict__ Fx,
                                              const float* __restrict__ Fc,
                                              u16* __restrict__ Xt, u16* __restrict__ Xlo,
                                              u8* __restrict__ Xf8) {
    __shared__ float tile[32][33];
    const int blk = blockIdx.x;               // 16384
    const int b = blk >> 11;
    const int rem = blk & 2047;
    const int hw0 = (rem >> 4) << 5;
    const int c0 = (rem & 15) << 5;           // 0..480
    const int tid = threadIdx.x;
    const int ci = tid >> 5, hwi = tid & 31;
#pragma unroll
    for (int it = 0; it < 4; ++it) {
        const int cc = c0 + ci + it * 8;
        const float* src = (cc < 256) ? Fx + (((size_t)b << 8) + cc) * HWc
                                      : Fc + (((size_t)b << 8) + cc - 256) * HWc;
        tile[ci + it * 8][hwi] = src[hw0 + hwi];
    }
    __syncthreads();
    const int pix = tid >> 3, c4 = (tid & 7) << 2;
    const size_t row = ((size_t)b << 12) + hw0 + pix;
    float v[4];
#pragma unroll
    for (int k = 0; k < 4; ++k) v[k] = tile[c4 + k][pix];
    ushort4 hi4, lo4;
#pragma unroll
    for (int k = 0; k < 4; ++k) {
        const u16 h = f2bf(v[k]);
        ((u16*)&hi4)[k] = h;
        ((u16*)&lo4)[k] = f2bf(v[k] - bf2f(h));
    }
    *(ushort4*)(Xt + row * 512 + c0 + c4) = hi4;
    *(ushort4*)(Xlo + row * 512 + c0 + c4) = lo4;
    if (c0 >= 256) {   // F_c half -> fp8 for the gather
        *(unsigned int*)(Xf8 + row * 256 + (c0 - 256) + c4) = pk4_fp8(v[0], v[1], v[2], v[3]);
    }
}

// ---------------- kernel 2: prep — wfuse fp8 + wconv swizzled blob + zpage ----------------
__global__ __launch_bounds__(256) void prep(const float* __restrict__ wf,
                                            u8* __restrict__ wf8,
                                            const float* __restrict__ w_off,
                                            const float* __restrict__ w_attn,
                                            u16* __restrict__ wconv,
                                            float* __restrict__ zpage) {
    const int tid = threadIdx.x;
    if (blockIdx.x < 256) {
        const int i = blockIdx.x * 256 + tid;     // 65536 groups of 4
        const float4 v = *(const float4*)(wf + (size_t)i * 4);
        *(unsigned int*)(wf8 + (size_t)i * 4) = pk4_fp8(v.x, v.y, v.z, v.w);
    } else if (blockIdx.x < 264) {            // EXACTLY 8 steps
        const int step = blockIdx.x - 256;
        for (int n = tid; n < 1728; n += 256) {
            const int par = n & 1;
            const int slot = (n >> 1) & 3;
            const int pair = (n >> 3) % 6;
            const int tap = (n / 48) % 9;
            const int prec = (n / 432) & 1;
            const int sub = n / 864;
            const int oc = pair * 2 + par;
            const int c = slot ^ (pair & 3);
            const int ch = step * 64 + sub * 32 + c * 8;
            u16x8 out;
#pragma unroll
            for (int j = 0; j < 8; ++j) {
                const float v = (oc < 8)
                    ? w_off[((size_t)oc * 512 + ch + j) * 9 + tap]
                    : w_attn[((size_t)(oc - 8) * 512 + ch + j) * 9 + tap];
                const u16 h = f2bf(v);
                out[j] = prec ? f2bf(v - bf2f(h)) : h;
            }
            *(u16x8*)(wconv + ((size_t)step * 1728 + n) * 8) = out;
        }
    } else {
        if (tid < 64) zpage[tid] = 0.f;
    }
}

// ---------------- kernel 3: conv as split-bf16 MFMA implicit GEMM (unchanged) ----------------
#define XBUF_STR 67584
#define XPRC_STR 33792
#define XROW_STR 8448
#define B_BASE   135168
__global__ __launch_bounds__(512) void conv_mfma(
    const u16* __restrict__ Xt, const u16* __restrict__ Xlo,
    const u16* __restrict__ wconv, const float* __restrict__ zpage,
    const float* __restrict__ b_off, const float* __restrict__ b_attn,
    float* __restrict__ dout, float* __restrict__ attnb, float* __restrict__ lossp) {
    __shared__ char smem[163840];

    const int tid = threadIdx.x;
    const int wv = tid >> 6, lane = tid & 63;
    const int gp = wv >> 2, qd = wv & 3;
    const int l15 = lane & 15, g = lane >> 4;
    const int b = blockIdx.x >> 5;
    const int h0 = (blockIdx.x & 31) * 2;
    const int wrow = qd >> 1, wcol0 = (qd & 1) * 32;

    if (tid < 256) {
        const int bu = tid >> 7, pr = (tid >> 6) & 1, rr = (tid >> 4) & 3;
        const int hp = (tid >> 3) & 1, cc = tid & 7;
        const int p = hp ? 65 : 0;
        const float4 z = {0.f, 0.f, 0.f, 0.f};
        *(float4*)(smem + bu * XBUF_STR + pr * XPRC_STR + rr * XROW_STR + p * 128 + cc * 16) = z;
    }

    int pre[2][3];
#pragma unroll
    for (int f = 0; f < 2; ++f)
#pragma unroll
        for (int dx = 0; dx < 3; ++dx) {
            const int p = wcol0 + f * 16 + l15 + dx;      // 0..65
            pre[f][dx] = wrow * XROW_STR + p * 128 + ((((gp << 2) | g) ^ (p & 7)) << 4);
        }
    const int bpair = l15 >> 1, bpar = l15 & 1;
    const int vb = B_BASE + gp * 13824 + bpair * 128 + ((g ^ (bpair & 3)) << 5) + bpar * 16;

    auto stage_X = [&](int step, int buf) {
#pragma unroll
        for (int k = 0; k < 9; ++k) {
            const int f = wv * 9 + k;                     // 0..71
            const int prec = f / 36, rr = (f / 9) & 3, i = f % 9;
            const int p = i * 8 + (lane >> 3);
            const int c = (lane & 7) ^ (p & 7);
            const int col = p - 1;
            const int h = h0 - 1 + rr;
            const bool act = (p >= 1) && (p <= 64);
            const u16* srcb = prec ? Xlo : Xt;
            const char* gsrc = (h >= 0 && h < 64)
                ? (const char*)(srcb + (((size_t)((b << 12) + h * 64 + col)) << 9) + step * 64 + c * 8)
                : (const char*)zpage + ((lane & 7) << 4);
            char* ldst = smem + buf * XBUF_STR + prec * XPRC_STR + rr * XROW_STR + i * 1024;
            if (act)
                __builtin_amdgcn_global_load_lds(
                    (const __attribute__((address_space(1))) unsigned int*)gsrc,
                    (__attribute__((address_space(3))) unsigned int*)ldst, 16, 0, 0);
        }
    };
    auto stage_B = [&](int step) {
        for (int i = wv; i < 27; i += 8) {
            const char* gsrc = (const char*)wconv + (((size_t)step * 1728) + i * 64 + lane) * 16;
            char* ldst = smem + B_BASE + i * 1024;
            __builtin_amdgcn_global_load_lds(
                (const __attribute__((address_space(1))) unsigned int*)gsrc,
                (__attribute__((address_space(3))) unsigned int*)ldst, 16, 0, 0);
        }
    };

    __syncthreads();
    stage_X(0, 0);
    stage_B(0);
    __syncthreads();

    f32x4 acc0 = {}, acc1 = {};

    for (int step = 0; step < 8; ++step) {
        if (step < 7) {
            stage_X(step + 1, (step + 1) & 1);
            asm volatile("s_waitcnt vmcnt(9)" ::: "memory");
        } else {
            asm volatile("s_waitcnt vmcnt(0)" ::: "memory");
        }
        __builtin_amdgcn_s_barrier();
        __builtin_amdgcn_sched_barrier(0);

#pragma unroll
        for (int tap = 0; tap < 9; ++tap) {
            const int dy = tap / 3, dx = tap % 3;
            const bf16x8 bh = *(const bf16x8*)(smem + vb + tap * 768);
            const bf16x8 bl = *(const bf16x8*)(smem + vb + 6912 + tap * 768);
            const bf16x8 a0h = *(const bf16x8*)(smem + pre[0][dx] + dy * XROW_STR);
            const bf16x8 a1h = *(const bf16x8*)(smem + pre[1][dx] + dy * XROW_STR);
            const bf16x8 a0l = *(const bf16x8*)(smem + pre[0][dx] + XPRC_STR + dy * XROW_STR);
            const bf16x8 a1l = *(const bf16x8*)(smem + pre[1][dx] + XPRC_STR + dy * XROW_STR);
            acc0 = __builtin_amdgcn_mfma_f32_16x16x32_bf16(a0h, bh, acc0, 0, 0, 0);
            acc1 = __builtin_amdgcn_mfma_f32_16x16x32_bf16(a1h, bh, acc1, 0, 0, 0);
            acc0 = __builtin_amdgcn_mfma_f32_16x16x32_bf16(a0h, bl, acc0, 0, 0, 0);
            acc1 = __builtin_amdgcn_mfma_f32_16x16x32_bf16(a1h, bl, acc1, 0, 0, 0);
            acc0 = __builtin_amdgcn_mfma_f32_16x16x32_bf16(a0l, bh, acc0, 0, 0, 0);
            acc1 = __builtin_amdgcn_mfma_f32_16x16x32_bf16(a1l, bh, acc1, 0, 0, 0);
        }

        __builtin_amdgcn_sched_barrier(0);
        __builtin_amdgcn_s_barrier();
        __builtin_amdgcn_sched_barrier(0);
        if (step < 7) stage_B(step + 1);
        const int d = (step & 1) ? -XBUF_STR : XBUF_STR;
#pragma unroll
        for (int f = 0; f < 2; ++f)
#pragma unroll
            for (int dx = 0; dx < 3; ++dx) pre[f][dx] += d;
    }

    __syncthreads();
    float* eL = (float*)smem;        // [2 groups][12 oc][128 pix]
    if (l15 < 12) {
#pragma unroll
        for (int r = 0; r < 4; ++r) {
            const int px0 = wrow * 64 + wcol0 + g * 4 + r;
            eL[(gp * 12 + l15) * 128 + px0] = acc0[r];
            eL[(gp * 12 + l15) * 128 + px0 + 16] = acc1[r];
        }
    }
    __syncthreads();
    float labs = 0.f;
    if (tid < 256) {
        const int oc = tid >> 5, seg = tid & 31;
        const float4 v0 = *(const float4*)&eL[oc * 128 + seg * 4];
        const float4 v1 = *(const float4*)&eL[(12 + oc) * 128 + seg * 4];
        const float bo = b_off[oc];
        float4 o;
        o.x = v0.x + v1.x + bo; o.y = v0.y + v1.y + bo;
        o.z = v0.z + v1.z + bo; o.w = v0.w + v1.w + bo;
        *(float4*)(dout + OFFS_BASE + (((size_t)b * 8 + oc) << 12) + h0 * 64 + seg * 4) = o;
        labs = fabsf(o.x) + fabsf(o.y) + fabsf(o.z) + fabsf(o.w);
    } else if (tid < 384) {
        const int t2 = tid - 256;
        const int oc = t2 >> 5, seg = t2 & 31;
        const float4 v0 = *(const float4*)&eL[(8 + oc) * 128 + seg * 4];
        const float4 v1 = *(const float4*)&eL[(20 + oc) * 128 + seg * 4];
        const float ba = b_attn[oc];
        float4 o;
        o.x = 1.f / (1.f + expf(-(v0.x + v1.x + ba)));
        o.y = 1.f / (1.f + expf(-(v0.y + v1.y + ba)));
        o.z = 1.f / (1.f + expf(-(v0.z + v1.z + ba)));
        o.w = 1.f / (1.f + expf(-(v0.w + v1.w + ba)));
        *(float4*)(attnb + (((size_t)b * 4 + (oc)) << 12) + h0 * 64 + seg * 4) = o;
    }
#pragma unroll
    for (int off = 32; off; off >>= 1) labs += __shfl_down(labs, off);
    float* wr = (float*)(smem + 14336);
    if (lane == 0) wr[wv] = labs;
    __syncthreads();
    if (tid == 0) {
        float s = 0.f;
#pragma unroll
        for (int i = 0; i < 8; ++i) s += wr[i];
        lossp[blockIdx.x] = s;
    }
}

// ---------------- kernel 4: loss reduce + alpha MLP ----------------
__global__ __launch_bounds__(256) void finalize_small(
    const float* __restrict__ lossp, const float* __restrict__ t,
    const float* __restrict__ w1, const float* __restrict__ b1,
    const float* __restrict__ w2, const float* __restrict__ b2,
    float* __restrict__ dout, float* __restrict__ alpha) {
    __shared__ float sd[4];
    const int tid = threadIdx.x;
    float s = lossp[tid];
#pragma unroll
    for (int off = 32; off; off >>= 1) s += __shfl_down(s, off);
    if ((tid & 63) == 0) sd[tid >> 6] = s;
    __syncthreads();
    if (tid == 0) dout[LOSS_IDX] = (sd[0] + sd[1] + sd[2] + sd[3]) * (1.f / 262144.f);

    for (int b = 0; b < 8; ++b) {
        __syncthreads();
        float v = 0.f;
        if (tid < 128) v = fmaxf(fmaf(t[b], w1[tid], b1[tid]), 0.f) * w2[tid];
#pragma unroll
        for (int off = 32; off; off >>= 1) v += __shfl_down(v, off);
        if ((tid & 63) == 0) sd[tid >> 6] = v;
        __syncthreads();
        if (tid == 0) alpha[b] = 1.f / (1.f + expf(-(sd[0] + sd[1] + b2[0])));
    }
}

// ---------------- kernel 5: bilinear gather (fp8) -> head (fp8) ----------------
__global__ __launch_bounds__(256) void sample_head(
    const u8* __restrict__ Xf8, const float* __restrict__ dout,
    const float* __restrict__ attnb, const float* __restrict__ Wp,
    u8* __restrict__ head) {
    const int tid = threadIdx.x;
    const int wv = tid >> 6, lane = tid & 63;
    const int item = blockIdx.x * 4 + wv;           // (b, m, p)
    const int b = item >> 14;
    const int m = (item >> 12) & 3;
    const int p = item & 4095;
    const int h = p >> 6, wc = p & 63;
    const int hl = lane >> 5, l32 = lane & 31;

    const float off0 = dout[OFFS_BASE + (((size_t)b * 8 + 2 * m) << 12) + p];
    const float off1 = dout[OFFS_BASE + (((size_t)b * 8 + 2 * m + 1) << 12) + p];
    const float a    = attnb[(((size_t)b * 4 + m) << 12) + p];

    const float ysh = -1.f + h * (2.f / 63.f);
    const float xsw = -1.f + wc * (2.f / 63.f);

    const u8* base = Xf8 + (((size_t)b << 12) << 8) + l32 * 8;   // F_c fp8, channel-last
    float acc[8] = {};

#pragma unroll
    for (int r = 0; r < 4; ++r) {
        const float bpy = (r < 2) ? -0.5f : 0.5f;
        const float bpx = (r & 1) ? 0.5f : -0.5f;
        const float c0 = ysh + bpy + off0;   // used as gx (reference quirk)
        const float c1 = xsw + bpx + off1;   // used as gy
        const float ix = (c0 + 1.f) * 31.5f;
        const float iy = (c1 + 1.f) * 31.5f;
        const float x0 = floorf(ix), y0 = floorf(iy);
        const float wx1 = ix - x0, wx0 = 1.f - wx1;
        const float wy1 = iy - y0, wy0 = 1.f - wy1;
        const float xf = x0 + hl;                        // this half-wave's x corner
        const float wxl = (hl ? wx1 : wx0) * (Wp[m * 4 + r] * a);   // attn+Wp folded in
        const bool xin = (xf >= 0.f) && (xf < 64.f);
        const bool v0 = xin && (y0 >= 0.f) && (y0 < 64.f);
        const bool v1 = xin && (y0 >= -1.f) && (y0 < 63.f);
        const int xi = (int)xf;
        uint2 u0, u1;
        if (v0) u0 = *(const uint2*)(base + ((size_t)((((int)y0) << 6) + xi)) * 256);
        if (v1) u1 = *(const uint2*)(base + ((size_t)((((int)y0 + 1) << 6) + xi)) * 256);
        if (v0) {
            const float w = wxl * wy0;
            const f32x2 pa = __builtin_amdgcn_cvt_pk_f32_fp8((int)u0.x, false);
            const f32x2 pb = __builtin_amdgcn_cvt_pk_f32_fp8((int)u0.x, true);
            const f32x2 pc = __builtin_amdgcn_cvt_pk_f32_fp8((int)u0.y, false);
            const f32x2 pd = __builtin_amdgcn_cvt_pk_f32_fp8((int)u0.y, true);
            acc[0] = fmaf(w, pa[0], acc[0]); acc[1] = fmaf(w, pa[1], acc[1]);
            acc[2] = fmaf(w, pb[0], acc[2]); acc[3] = fmaf(w, pb[1], acc[3]);
            acc[4] = fmaf(w, pc[0], acc[4]); acc[5] = fmaf(w, pc[1], acc[5]);
            acc[6] = fmaf(w, pd[0], acc[6]); acc[7] = fmaf(w, pd[1], acc[7]);
        }
        if (v1) {
            const float w = wxl * wy1;
            const f32x2 pa = __builtin_amdgcn_cvt_pk_f32_fp8((int)u1.x, false);
            const f32x2 pb = __builtin_amdgcn_cvt_pk_f32_fp8((int)u1.x, true);
            const f32x2 pc = __builtin_amdgcn_cvt_pk_f32_fp8((int)u1.y, false);
            const f32x2 pd = __builtin_amdgcn_cvt_pk_f32_fp8((int)u1.y, true);
            acc[0] = fmaf(w, pa[0], acc[0]); acc[1] = fmaf(w, pa[1], acc[1]);
            acc[2] = fmaf(w, pb[0], acc[2]); acc[3] = fmaf(w, pb[1], acc[3]);
            acc[4] = fmaf(w, pc[0], acc[4]); acc[5] = fmaf(w, pc[1], acc[5]);
            acc[6] = fmaf(w, pd[0], acc[6]); acc[7] = fmaf(w, pd[1], acc[7]);
        }
    }
#pragma unroll
    for (int j = 0; j < 8; ++j) acc[j] += __shfl_xor(acc[j], 32);
    if (lane < 32) {
        uint2 o;
        o.x = pk4_fp8(acc[0], acc[1], acc[2], acc[3]);
        o.y = pk4_fp8(acc[4], acc[5], acc[6], acc[7]);
        *(uint2*)(head + ((((size_t)b << 12) + p)) * KDIM + m * 256 + l32 * 8) = o;
    }
}

// ---------------- kernel 6: fuse GEMM v4 — fp8 MFMA, K-tile 64, swizzled global_load_lds ----------------
// LDS per matrix per buf: [128 rows][64 B]; 16B-chunk slot s holds global chunk s ^ ((row>>1)&3).
__global__ __launch_bounds__(256) void fuse_gemm(
    const u8* __restrict__ head, const u8* __restrict__ wf8,
    const float* __restrict__ Fx, const float* __restrict__ bfuse,
    const float* __restrict__ alpha, float* __restrict__ dout) {
    __shared__ __attribute__((aligned(16))) char smem[2][2][8192];   // [buf][A/B][128*64]

    const int tid = threadIdx.x;
    const int lane = tid & 63, wv = tid >> 6;
    const int wm = wv >> 1, wn = wv & 1;
    const int l15 = lane & 15, g = lane >> 4;
    const size_t arow0 = (size_t)blockIdx.x * 128;
    const int co0 = blockIdx.y * 128;

    f32x4 acc[4][4] = {};

    // staging: waves 0,1 -> A halves; waves 2,3 -> B halves. 4 instrs/wave/tile.
    const int isB = wv >> 1;
    const int whalf = wv & 1;
    const u8* srcbase = isB ? wf8 + (size_t)co0 * KDIM : head + arow0 * KDIM;

    auto stage = [&](int kt, int buf) {
#pragma unroll
        for (int i = 0; i < 4; ++i) {
            const int row = whalf * 64 + i * 16 + (lane >> 2);
            const int gq = (lane & 3) ^ ((row >> 1) & 3);          // global 16B chunk
            const u8* gsrc = srcbase + (size_t)row * KDIM + kt * 64 + gq * 16;
            char* ldst = smem[buf][isB] + (whalf * 64 + i * 16) * 64;   // + lane*16 by HW
            __builtin_amdgcn_global_load_lds(
                (const __attribute__((address_space(1))) unsigned int*)gsrc,
                (__attribute__((address_space(3))) unsigned int*)ldst, 16, 0, 0);
        }
    };

    stage(0, 0);
    __syncthreads();

    for (int kt = 0; kt < 16; ++kt) {
        if (kt < 15) {
            stage(kt + 1, (kt + 1) & 1);
            asm volatile("s_waitcnt vmcnt(4)" ::: "memory");   // own tile-kt loads done
        } else {
            asm volatile("s_waitcnt vmcnt(0)" ::: "memory");
        }
        __builtin_amdgcn_s_barrier();
        __builtin_amdgcn_sched_barrier(0);

        const char* Ab = smem[kt & 1][0];
        const char* Bb = smem[kt & 1][1];
#pragma unroll
        for (int s = 0; s < 2; ++s) {                      // two K=32 steps per tile
            const int gg = s * 4 + g;                      // global 8B k-granule
            long av[4], bv[4];
#pragma unroll
            for (int f = 0; f < 4; ++f) {
                const int ra = wm * 64 + f * 16 + l15;
                const int rb = wn * 64 + f * 16 + l15;
                const int sa = (gg >> 1) ^ ((ra >> 1) & 3);
                const int sb = (gg >> 1) ^ ((rb >> 1) & 3);
                av[f] = *(const long*)(Ab + ra * 64 + sa * 16 + (gg & 1) * 8);
                bv[f] = *(const long*)(Bb + rb * 64 + sb * 16 + (gg & 1) * 8);
            }
#pragma unroll
            for (int i = 0; i < 4; ++i)
#pragma unroll
                for (int j = 0; j < 4; ++j)
                    acc[i][j] = __builtin_amdgcn_mfma_f32_16x16x32_fp8_fp8(av[i], bv[j], acc[i][j], 0, 0, 0);
        }

        __builtin_amdgcn_sched_barrier(0);
        __builtin_amdgcn_s_barrier();       // all waves done reading before next overwrite
        __builtin_amdgcn_sched_barrier(0);
    }

    const int b = (int)(arow0 >> 12);
    const float al = alpha[b], il = 1.f - al;
    const int pixbase = (int)(arow0 & 4095);
#pragma unroll
    for (int i = 0; i < 4; ++i) {
        const int rowl = wm * 64 + i * 16 + g * 4;
        const int pix = pixbase + rowl;
#pragma unroll
        for (int j = 0; j < 4; ++j) {
            const int co = co0 + wn * 64 + j * 16 + l15;
            const float bias = bfuse[co];
            const size_t idx = (((size_t)b << 8) + co) * HWc + pix;
            const float4 fx = *(const float4*)(Fx + idx);
            const f32x4 v = acc[i][j];
            float4 o;
            o.x = al * (v[0] + bias) + il * fx.x;
            o.y = al * (v[1] + bias) + il * fx.y;
            o.z = al * (v[2] + bias) + il * fx.z;
            o.w = al * (v[3] + bias) + il * fx.w;
            *(float4*)(dout + idx) = o;
        }
    }
}

// ---------------- launcher ----------------
extern "C" void kernel_launch(void* const* d_in, const int* in_sizes, int n_in,
                              void* d_out, int out_size, void* d_ws, size_t ws_size,
                              hipStream_t stream) {
    const float* F_x    = (const float*)d_in[0];
    const float* F_c    = (const float*)d_in[1];
    const float* t      = (const float*)d_in[2];
    const float* w_off  = (const float*)d_in[3];
    const float* b_off  = (const float*)d_in[4];
    const float* w_attn = (const float*)d_in[5];
    const float* b_attn = (const float*)d_in[6];
    const float* Wp     = (const float*)d_in[7];
    const float* w_fuse = (const float*)d_in[8];
    const float* b_fuse = (const float*)d_in[9];
    const float* w1     = (const float*)d_in[10];
    const float* b1     = (const float*)d_in[11];
    const float* w2     = (const float*)d_in[12];
    const float* b2     = (const float*)d_in[13];
    float* out = (float*)d_out;

    char* ws = (char*)d_ws;
    u16*   Xt    = (u16*)(ws + XT_OFF);
    u16*   Xlo   = (u16*)(ws + HEAD_OFF);     // conv-only; dead before head write
    u8*    head8 = (u8*)(ws + HEAD_OFF);      // fp8 head, 32 MB
    u8*    Xf8   = (u8*)(ws + XF8_OFF);
    u8*    wf8   = (u8*)(ws + WBF_OFF);
    float* attnb = (float*)(ws + ATTN_OFF);
    float* alphb = (float*)(ws + ALPHA_OFF);
    float* lossp = (float*)(ws + LOSSP_OFF);
    u16*   wconv = (u16*)(ws + WREP_OFF);
    float* zpage = (float*)(ws + ZPAGE_OFF);

    pack_x<<<dim3(16384), dim3(256), 0, stream>>>(F_x, F_c, Xt, Xlo, Xf8);
    prep<<<dim3(265), dim3(256), 0, stream>>>(w_fuse, wf8, w_off, w_attn, wconv, zpage);
    conv_mfma<<<dim3(256), dim3(512), 0, stream>>>(Xt, Xlo, wconv, zpage, b_off, b_attn,
                                                   out, attnb, lossp);
    finalize_small<<<dim3(1), dim3(256), 0, stream>>>(lossp, t, w1, b1, w2, b2, out, alphb);
    sample_head<<<dim3(32768), dim3(256), 0, stream>>>(Xf8, out, attnb, Wp, head8);
    fuse_gemm<<<dim3(256, 2), dim3(256), 0, stream>>>(head8, wf8, F_x, b_fuse, alphb, out);
}